// Round 4
// baseline (1512.186 us; speedup 1.0000x reference)
//
#include <hip/hip_runtime.h>

#define NN 50000
#define EE 600000
#define DD 128
#define DD2 256
#define LL 5
#define BN_EPS 1e-5f

typedef __attribute__((ext_vector_type(8))) _Float16 half8;
typedef __attribute__((ext_vector_type(4))) float f32x4;

__device__ inline unsigned short f2h_bits(float f) {
    _Float16 h = (_Float16)f;  // RTNE
    return __builtin_bit_cast(unsigned short, h);
}
__device__ inline float h2f(unsigned short u) {
    return (float)__builtin_bit_cast(_Float16, u);
}

// ---------------- CSR build ----------------

__global__ void hist_kernel(const int* __restrict__ dst, int* __restrict__ counts) {
    int e = blockIdx.x * blockDim.x + threadIdx.x;
    if (e < EE) atomicAdd(&counts[dst[e]], 1);
}

__global__ void scan1_kernel(const int* __restrict__ counts, int* __restrict__ row_ptr,
                             int* __restrict__ blksum) {
    __shared__ int tmp[256];
    int i = blockIdx.x * 256 + threadIdx.x;
    int v = (i < NN) ? counts[i] : 0;
    tmp[threadIdx.x] = v;
    __syncthreads();
    for (int off = 1; off < 256; off <<= 1) {
        int x = 0;
        if (threadIdx.x >= off) x = tmp[threadIdx.x - off];
        __syncthreads();
        if (threadIdx.x >= off) tmp[threadIdx.x] += x;
        __syncthreads();
    }
    if (i < NN) row_ptr[i] = tmp[threadIdx.x] - v;
    if (threadIdx.x == 255) blksum[blockIdx.x] = tmp[255];
}

__global__ void scan2_kernel(int* __restrict__ blksum, int nblocks) {
    __shared__ int tmp[256];
    int v = (threadIdx.x < nblocks) ? blksum[threadIdx.x] : 0;
    tmp[threadIdx.x] = v;
    __syncthreads();
    for (int off = 1; off < 256; off <<= 1) {
        int x = 0;
        if (threadIdx.x >= off) x = tmp[threadIdx.x - off];
        __syncthreads();
        if (threadIdx.x >= off) tmp[threadIdx.x] += x;
        __syncthreads();
    }
    blksum[threadIdx.x] = tmp[threadIdx.x] - v;
}

__global__ void scan3_kernel(int* __restrict__ row_ptr, const int* __restrict__ blksum) {
    int i = blockIdx.x * 256 + threadIdx.x;
    if (i < NN) row_ptr[i] += blksum[blockIdx.x];
    if (i == 0) row_ptr[NN] = EE;
}

// scatter + pack edge data: edata[p] = {src, a0|a1<<8|a2<<16, w_bits, 0}
__global__ void scatter_kernel(const int* __restrict__ dst, const int* __restrict__ src,
                               const int* __restrict__ edge_attr, const float* __restrict__ ew,
                               const int* __restrict__ row_ptr, int* __restrict__ cursor,
                               int4* __restrict__ edata) {
    int e = blockIdx.x * blockDim.x + threadIdx.x;
    if (e < EE) {
        int d = dst[e];
        int p = row_ptr[d] + atomicAdd(&cursor[d], 1);
        int4 v;
        v.x = src[e];
        v.y = edge_attr[3 * e + 0] | (edge_attr[3 * e + 1] << 8) | (edge_attr[3 * e + 2] << 16);
        v.z = __float_as_int(ew[e]);
        v.w = 0;
        edata[p] = v;
    }
}

// ---------------- W transpose to fp16: Wt[l][m][k] = fp16(W[l][k][m]) ----------------

template <int K, int M>
__global__ void transpose_w_kernel(const float* __restrict__ W, unsigned short* __restrict__ Wt) {
    int idx = blockIdx.x * 256 + threadIdx.x;  // over L*K*M
    if (idx >= LL * K * M) return;
    int l = idx / (K * M);
    int rem = idx - l * K * M;
    int k = rem / M;
    int m = rem - k * M;
    Wt[(size_t)l * K * M + (size_t)m * K + k] = f2h_bits(W[idx]);
}

// ---------------- node init (fp32 h) ----------------

__global__ void init_h_kernel(const int* __restrict__ x, const float* __restrict__ atom_emb,
                              float* __restrict__ h) {
    int n = blockIdx.x * 8 + (threadIdx.x >> 5);
    int lane = threadIdx.x & 31;
    if (n >= NN) return;
    float a0 = 0.f, a1 = 0.f, a2 = 0.f, a3 = 0.f;
#pragma unroll
    for (int f = 0; f < 9; f++) {
        int idx = x[n * 9 + f];
        const float4 v = *(const float4*)(atom_emb + ((size_t)(f * 64 + idx) * DD) + lane * 4);
        a0 += v.x; a1 += v.y; a2 += v.z; a3 += v.w;
    }
    float4 o; o.x = a0; o.y = a1; o.z = a2; o.w = a3;
    *(float4*)(h + (size_t)n * DD + lane * 4) = o;
}

// ---------------- edge aggregate → A fp16 ----------------

__global__ void agg_kernel(const float* __restrict__ h, const int* __restrict__ row_ptr,
                           const int4* __restrict__ edata, const float* __restrict__ bond_l,
                           const float* __restrict__ eps_ptr, unsigned short* __restrict__ Aout) {
    int n = blockIdx.x * 8 + (threadIdx.x >> 5);
    int lane = threadIdx.x & 31;
    if (n >= NN) return;
    int beg = row_ptr[n], end = row_ptr[n + 1];
    float a0 = 0.f, a1 = 0.f, a2 = 0.f, a3 = 0.f;
    for (int i = beg; i < end; i++) {
        int4 ed = edata[i];
        int s = ed.x;
        int at = ed.y;
        float w = __int_as_float(ed.z);
        const float4 hv = *(const float4*)(h + (size_t)s * DD + lane * 4);
        const float4 b0 = *(const float4*)(bond_l + (size_t)((at & 0xff)) * DD + lane * 4);
        const float4 b1 = *(const float4*)(bond_l + (size_t)(8 + ((at >> 8) & 0xff)) * DD + lane * 4);
        const float4 b2 = *(const float4*)(bond_l + (size_t)(16 + ((at >> 16) & 0xff)) * DD + lane * 4);
        float m0 = fmaxf(hv.x + b0.x + b1.x + b2.x, 0.f);
        float m1 = fmaxf(hv.y + b0.y + b1.y + b2.y, 0.f);
        float m2 = fmaxf(hv.z + b0.z + b1.z + b2.z, 0.f);
        float m3 = fmaxf(hv.w + b0.w + b1.w + b2.w, 0.f);
        a0 += m0 * w; a1 += m1 * w; a2 += m2 * w; a3 += m3 * w;
    }
    float eps1 = 1.f + eps_ptr[0];
    const float4 hs = *(const float4*)(h + (size_t)n * DD + lane * 4);
    ushort4 o;
    o.x = f2h_bits(eps1 * hs.x + a0);
    o.y = f2h_bits(eps1 * hs.y + a1);
    o.z = f2h_bits(eps1 * hs.z + a2);
    o.w = f2h_bits(eps1 * hs.w + a3);
    *(ushort4*)(Aout + (size_t)n * DD + lane * 4) = o;
}

// ---------------- fp16 MFMA GEMM with register-resident B + full A prefetch ----------------
// C(NN x M) = A(NN x K) @ Bt^T + bias. A row-major fp16 bits, Bt [M][K] fp16 bits.
// HALF_OUT: C written as fp16 bits, else fp32.
// Stats: per-(rowblock,wave-row) partial sums written non-atomically to
// pstats[rb*M + c] (sum) and pstats[(NR+rb)*M + c] (sumsq), rb = blockIdx.x*2+wr,
// NR = 2*gridDim.x. Reduced by reduce_stats_kernel.

template <int K, int M, bool HALF_OUT>
__global__ __launch_bounds__(256, 3) void mfma_gemm_kernel(const unsigned short* __restrict__ A,
                                                           const unsigned short* __restrict__ Bt,
                                                           const float* __restrict__ bias,
                                                           void* __restrict__ Cv,
                                                           float* __restrict__ pstats) {
    const int KS = K / 32;
    int wave = threadIdx.x >> 6;
    int lane = threadIdx.x & 63;
    int wr = wave >> 1, wc = wave & 1;
    int row0 = blockIdx.x * 64 + wr * 32;
    int col0 = blockIdx.y * 64 + wc * 32;
    int lr = lane & 15;
    int q = lane >> 4;

    // hoist all B fragments into registers (column stripe is wave-private)
    half8 b[2][KS];
#pragma unroll
    for (int j = 0; j < 2; j++) {
        const unsigned short* bp = Bt + (size_t)(col0 + j * 16 + lr) * K + q * 8;
#pragma unroll
        for (int ks = 0; ks < KS; ks++)
            b[j][ks] = __builtin_bit_cast(half8, *(const int4*)(bp + ks * 32));
    }
    // prefetch all A fragments
    half8 a[2][KS];
#pragma unroll
    for (int i = 0; i < 2; i++) {
        int row = row0 + i * 16 + lr;
        const unsigned short* ap = A + (size_t)row * K + q * 8;
#pragma unroll
        for (int ks = 0; ks < KS; ks++) {
            int4 t = {0, 0, 0, 0};
            if (row < NN) t = *(const int4*)(ap + ks * 32);
            a[i][ks] = __builtin_bit_cast(half8, t);
        }
    }

    f32x4 acc[2][2];
#pragma unroll
    for (int i = 0; i < 2; i++)
#pragma unroll
        for (int j = 0; j < 2; j++) acc[i][j] = (f32x4){0.f, 0.f, 0.f, 0.f};

#pragma unroll
    for (int ks = 0; ks < KS; ks++)
#pragma unroll
        for (int i = 0; i < 2; i++)
#pragma unroll
            for (int j = 0; j < 2; j++)
                acc[i][j] = __builtin_amdgcn_mfma_f32_16x16x32_f16(a[i][ks], b[j][ks], acc[i][j], 0, 0, 0);

    // epilogue: D element (row = row0 + i*16 + q*4 + r, col = col0 + j*16 + lr)
    int NR = 2 * gridDim.x;
    int rb = blockIdx.x * 2 + wr;
#pragma unroll
    for (int j = 0; j < 2; j++) {
        int c = col0 + j * 16 + lr;
        float bi = bias[c];
        float s = 0.f, sq = 0.f;
#pragma unroll
        for (int i = 0; i < 2; i++) {
#pragma unroll
            for (int r = 0; r < 4; r++) {
                int row = row0 + i * 16 + q * 4 + r;
                float v = 0.f;
                if (row < NN) {
                    v = acc[i][j][r] + bi;
                    if (HALF_OUT)
                        ((unsigned short*)Cv)[(size_t)row * M + c] = f2h_bits(v);
                    else
                        ((float*)Cv)[(size_t)row * M + c] = v;
                }
                s += v;
                sq += v * v;
            }
        }
        s += __shfl_xor(s, 16);
        s += __shfl_xor(s, 32);
        sq += __shfl_xor(sq, 16);
        sq += __shfl_xor(sq, 32);
        if (q == 0) {
            pstats[(size_t)rb * M + c] = s;
            pstats[((size_t)NR + rb) * M + c] = sq;
        }
    }
}

// ---------------- stats tree-reduce: stats[c] = sum_rb pstats[rb][c] ----------------

__global__ void reduce_stats_kernel(const float* __restrict__ pstats, float* __restrict__ stats,
                                    int M, int NR) {
    int c = threadIdx.x;  // blockDim.x == M
    int chunk = (NR + gridDim.x - 1) / gridDim.x;
    int r0 = blockIdx.x * chunk;
    int r1 = r0 + chunk;
    if (r1 > NR) r1 = NR;
    float s = 0.f, q = 0.f;
    for (int r = r0; r < r1; r++) {
        s += pstats[(size_t)r * M + c];
        q += pstats[((size_t)NR + r) * M + c];
    }
    atomicAdd(&stats[c], s);
    atomicAdd(&stats[M + c], q);
}

// ---------------- BN finalize ----------------

__global__ void bn_finalize_kernel(const float* __restrict__ stats, const float* __restrict__ g,
                                   const float* __restrict__ b, float* __restrict__ s_out,
                                   float* __restrict__ t_out, int M) {
    int c = threadIdx.x;
    if (c >= M) return;
    float mean = stats[c] * (1.f / NN);
    float var = stats[M + c] * (1.f / NN) - mean * mean;
    float sc = g[c] * rsqrtf(var + BN_EPS);
    s_out[c] = sc;
    t_out[c] = b[c] - mean * sc;
}

// ---------------- BN apply 1: z1 fp16 -> fp16 with relu (8 elems/thread, M=256) ----------------

__global__ void bnapply1_kernel(const unsigned short* __restrict__ z, const float* __restrict__ s,
                                const float* __restrict__ t, unsigned short* __restrict__ o) {
    int i = (blockIdx.x * 256 + threadIdx.x) * 8;  // NN*256 total
    int c0 = i & 255;
    uint4 in = *(const uint4*)(z + i);
    unsigned int w[4] = {in.x, in.y, in.z, in.w};
    uint4 out;
    unsigned int* po = (unsigned int*)&out;
#pragma unroll
    for (int k = 0; k < 4; k++) {
        int c = c0 + 2 * k;
        float v0 = fmaxf(h2f((unsigned short)(w[k] & 0xffff)) * s[c] + t[c], 0.f);
        float v1 = fmaxf(h2f((unsigned short)(w[k] >> 16)) * s[c + 1] + t[c + 1], 0.f);
        po[k] = (unsigned int)f2h_bits(v0) | ((unsigned int)f2h_bits(v1) << 16);
    }
    *(uint4*)(o + i) = out;
}

// ---------------- BN apply 2: z2 fp32 -> fp32 out (optional relu), M=128 ----------------

__global__ void bnapply2_kernel(const float* __restrict__ z, const float* __restrict__ s,
                                const float* __restrict__ t, float* __restrict__ o, int do_relu) {
    int i = (blockIdx.x * 256 + threadIdx.x) * 4;  // NN*128 total
    int c = i & 127;
    float4 in = *(const float4*)(z + i);
    float v0 = in.x * s[c] + t[c];
    float v1 = in.y * s[c + 1] + t[c + 1];
    float v2 = in.z * s[c + 2] + t[c + 2];
    float v3 = in.w * s[c + 3] + t[c + 3];
    if (do_relu) {
        v0 = fmaxf(v0, 0.f); v1 = fmaxf(v1, 0.f);
        v2 = fmaxf(v2, 0.f); v3 = fmaxf(v3, 0.f);
    }
    float4 out; out.x = v0; out.y = v1; out.z = v2; out.w = v3;
    *(float4*)(o + i) = out;
}

// ---------------- launch ----------------

extern "C" void kernel_launch(void* const* d_in, const int* in_sizes, int n_in,
                              void* d_out, int out_size, void* d_ws, size_t ws_size,
                              hipStream_t stream) {
    const int* x = (const int*)d_in[0];
    const int* edge_index = (const int*)d_in[1];
    const int* edge_attr = (const int*)d_in[2];
    const float* edge_weight = (const float*)d_in[3];
    const float* atom_emb = (const float*)d_in[4];
    const float* bond_emb = (const float*)d_in[5];
    const float* W1 = (const float*)d_in[6];
    const float* b1 = (const float*)d_in[7];
    const float* bn1_g = (const float*)d_in[8];
    const float* bn1_b = (const float*)d_in[9];
    const float* W2 = (const float*)d_in[10];
    const float* b2 = (const float*)d_in[11];
    const float* eps_p = (const float*)d_in[12];
    const float* bn_g = (const float*)d_in[13];
    const float* bn_b = (const float*)d_in[14];
    const int* srcv = edge_index;
    const int* dstv = edge_index + EE;

    char* p = (char*)d_ws;
    auto alloc = [&](size_t bytes) {
        void* r = (void*)p;
        p += (bytes + 255) & ~(size_t)255;
        return r;
    };
    float* h = (float*)alloc((size_t)NN * DD * 4);                 // fp32 node state
    char* blockA = (char*)alloc((size_t)NN * DD * 4);
    unsigned short* A1h = (unsigned short*)blockA;                 // agg out fp16
    float* z2 = (float*)blockA;                                    // gemm2 out fp32 (A1h dead by then)
    unsigned short* z1 = (unsigned short*)alloc((size_t)NN * DD2 * 2);   // gemm1 out fp16
    unsigned short* z1h = (unsigned short*)alloc((size_t)NN * DD2 * 2);  // bn1+relu fp16
    int4* edata = (int4*)alloc((size_t)EE * 16);
    int* counts = (int*)alloc((size_t)NN * 4);
    int* row_ptr = (int*)alloc((size_t)(NN + 1) * 4);
    int* blksum = (int*)alloc(256 * 4);
    unsigned short* W1t = (unsigned short*)alloc((size_t)LL * DD * DD2 * 2);
    unsigned short* W2t = (unsigned short*)alloc((size_t)LL * DD * DD2 * 2);
    float* stats = (float*)alloc(1024 * 4);   // sum1[256] sq1[256] | sum2[128] sq2[128]
    float* sbuf = (float*)alloc(1024 * 4);    // s1[256] t1[256] s2[128] t2[128]
    float* pstats = (float*)alloc((size_t)2 * 1564 * 256 * 4);  // partial stats (max use)

    const int GR = (NN + 63) / 64;  // 782 row blocks
    const int NR = 2 * GR;          // 1564 partial rows

    // --- one-time prep ---
    hipMemsetAsync(counts, 0, (size_t)NN * 4, stream);
    hist_kernel<<<(EE + 255) / 256, 256, 0, stream>>>(dstv, counts);
    int nblk = (NN + 255) / 256;
    scan1_kernel<<<nblk, 256, 0, stream>>>(counts, row_ptr, blksum);
    scan2_kernel<<<1, 256, 0, stream>>>(blksum, nblk);
    scan3_kernel<<<nblk, 256, 0, stream>>>(row_ptr, blksum);
    hipMemsetAsync(counts, 0, (size_t)NN * 4, stream);
    scatter_kernel<<<(EE + 255) / 256, 256, 0, stream>>>(dstv, srcv, edge_attr, edge_weight,
                                                         row_ptr, counts, edata);
    transpose_w_kernel<DD, DD2><<<(LL * DD * DD2 + 255) / 256, 256, 0, stream>>>(W1, W1t);
    transpose_w_kernel<DD2, DD><<<(LL * DD * DD2 + 255) / 256, 256, 0, stream>>>(W2, W2t);
    init_h_kernel<<<(NN + 7) / 8, 256, 0, stream>>>(x, atom_emb, h);

    for (int l = 0; l < LL; l++) {
        agg_kernel<<<(NN + 7) / 8, 256, 0, stream>>>(h, row_ptr, edata,
                                                     bond_emb + (size_t)l * 3 * 8 * DD,
                                                     eps_p + l, A1h);

        hipMemsetAsync(stats, 0, 1024 * 4, stream);
        mfma_gemm_kernel<DD, DD2, true><<<dim3(GR, DD2 / 64), 256, 0, stream>>>(
            A1h, W1t + (size_t)l * DD * DD2, b1 + l * DD2, z1, pstats);
        reduce_stats_kernel<<<8, DD2, 0, stream>>>(pstats, stats, DD2, NR);
        bn_finalize_kernel<<<1, 256, 0, stream>>>(stats, bn1_g + l * DD2, bn1_b + l * DD2,
                                                  sbuf, sbuf + 256, DD2);
        bnapply1_kernel<<<(NN * DD2 / 8 + 255) / 256, 256, 0, stream>>>(z1, sbuf, sbuf + 256, z1h);

        mfma_gemm_kernel<DD2, DD, false><<<dim3(GR, DD / 64), 256, 0, stream>>>(
            z1h, W2t + (size_t)l * DD * DD2, b2 + l * DD, z2, pstats);
        reduce_stats_kernel<<<8, DD, 0, stream>>>(pstats, stats + 512, DD, NR);
        bn_finalize_kernel<<<1, 128, 0, stream>>>(stats + 512, bn_g + l * DD, bn_b + l * DD,
                                                  sbuf + 512, sbuf + 640, DD);
        bnapply2_kernel<<<(NN * DD / 4 + 255) / 256, 256, 0, stream>>>(
            z2, sbuf + 512, sbuf + 640, (l == LL - 1) ? (float*)d_out : h, (l < LL - 1) ? 1 : 0);
    }
}

// Round 5
// 1336.878 us; speedup vs baseline: 1.1311x; 1.1311x over previous
//
#include <hip/hip_runtime.h>

#define NN 50000
#define EE 600000
#define DD 128
#define DD2 256
#define LL 5
#define BN_EPS 1e-5f

typedef __attribute__((ext_vector_type(8))) _Float16 half8;
typedef __attribute__((ext_vector_type(4))) float f32x4;

__device__ inline unsigned short f2h_bits(float f) {
    _Float16 h = (_Float16)f;  // RTNE
    return __builtin_bit_cast(unsigned short, h);
}
__device__ inline float h2f(unsigned short u) {
    return (float)__builtin_bit_cast(_Float16, u);
}

// ---------------- CSR build ----------------

__global__ void hist_kernel(const int* __restrict__ dst, int* __restrict__ counts) {
    int e = blockIdx.x * blockDim.x + threadIdx.x;
    if (e < EE) atomicAdd(&counts[dst[e]], 1);
}

__global__ void scan1_kernel(const int* __restrict__ counts, int* __restrict__ row_ptr,
                             int* __restrict__ blksum) {
    __shared__ int tmp[256];
    int i = blockIdx.x * 256 + threadIdx.x;
    int v = (i < NN) ? counts[i] : 0;
    tmp[threadIdx.x] = v;
    __syncthreads();
    for (int off = 1; off < 256; off <<= 1) {
        int x = 0;
        if (threadIdx.x >= off) x = tmp[threadIdx.x - off];
        __syncthreads();
        if (threadIdx.x >= off) tmp[threadIdx.x] += x;
        __syncthreads();
    }
    if (i < NN) row_ptr[i] = tmp[threadIdx.x] - v;
    if (threadIdx.x == 255) blksum[blockIdx.x] = tmp[255];
}

__global__ void scan2_kernel(int* __restrict__ blksum, int nblocks) {
    __shared__ int tmp[256];
    int v = (threadIdx.x < nblocks) ? blksum[threadIdx.x] : 0;
    tmp[threadIdx.x] = v;
    __syncthreads();
    for (int off = 1; off < 256; off <<= 1) {
        int x = 0;
        if (threadIdx.x >= off) x = tmp[threadIdx.x - off];
        __syncthreads();
        if (threadIdx.x >= off) tmp[threadIdx.x] += x;
        __syncthreads();
    }
    blksum[threadIdx.x] = tmp[threadIdx.x] - v;
}

__global__ void scan3_kernel(int* __restrict__ row_ptr, const int* __restrict__ blksum) {
    int i = blockIdx.x * 256 + threadIdx.x;
    if (i < NN) row_ptr[i] += blksum[blockIdx.x];
    if (i == 0) row_ptr[NN] = EE;
}

// scatter + pack edge data: edata[p] = {src, cid | w_fp16<<16}, cid = a0 + 8*a1 + 64*a2
__global__ void scatter_kernel(const int* __restrict__ dst, const int* __restrict__ src,
                               const int* __restrict__ edge_attr, const float* __restrict__ ew,
                               const int* __restrict__ row_ptr, int* __restrict__ cursor,
                               uint2* __restrict__ edata) {
    int e = blockIdx.x * blockDim.x + threadIdx.x;
    if (e < EE) {
        int d = dst[e];
        int p = row_ptr[d] + atomicAdd(&cursor[d], 1);
        int cid = edge_attr[3 * e + 0] + 8 * edge_attr[3 * e + 1] + 64 * edge_attr[3 * e + 2];
        uint2 v;
        v.x = (unsigned)src[e];
        v.y = (unsigned)cid | ((unsigned)f2h_bits(ew[e]) << 16);
        edata[p] = v;
    }
}

// ---------------- table prep: W1t, W2t (fp16, [M][K]) + combined bond table (fp16) ------------
// bsum[l][cid][d] = sum_f bond_emb[l][f][a_f][d], cid = a0+8*a1+64*a2

__global__ void prep_tables_kernel(const float* __restrict__ W1, const float* __restrict__ W2,
                                   const float* __restrict__ bond_emb,
                                   unsigned short* __restrict__ W1t,
                                   unsigned short* __restrict__ W2t,
                                   unsigned short* __restrict__ bsum) {
    const int NW = LL * DD * DD2;  // 163840
    int idx = blockIdx.x * 256 + threadIdx.x;
    if (idx < NW) {
        int l = idx / (DD * DD2);
        int rem = idx - l * DD * DD2;
        int k = rem / DD2, m = rem - k * DD2;  // W1: [L][128][256]
        W1t[(size_t)l * DD * DD2 + (size_t)m * DD + k] = f2h_bits(W1[idx]);
    } else if (idx < 2 * NW) {
        int j = idx - NW;
        int l = j / (DD * DD2);
        int rem = j - l * DD * DD2;
        int k = rem / DD, m = rem - k * DD;  // W2: [L][256][128]
        W2t[(size_t)l * DD * DD2 + (size_t)m * DD2 + k] = f2h_bits(W2[j]);
    } else if (idx < 2 * NW + LL * 512 * DD) {
        int j = idx - 2 * NW;
        int l = j >> 16;          // 512*128 = 65536
        int rem = j & 65535;
        int cid = rem >> 7, d = rem & 127;
        int a0 = cid & 7, a1 = (cid >> 3) & 7, a2 = cid >> 6;
        const float* base = bond_emb + (size_t)l * 3 * 8 * DD;
        bsum[j] = f2h_bits(base[a0 * DD + d] + base[(8 + a1) * DD + d] + base[(16 + a2) * DD + d]);
    }
}

// ---------------- node init (fp16 h) ----------------

__global__ void init_h_kernel(const int* __restrict__ x, const float* __restrict__ atom_emb,
                              unsigned short* __restrict__ h) {
    int n = blockIdx.x * 8 + (threadIdx.x >> 5);
    int lane = threadIdx.x & 31;
    float a0 = 0.f, a1 = 0.f, a2 = 0.f, a3 = 0.f;
#pragma unroll
    for (int f = 0; f < 9; f++) {
        int idx = x[n * 9 + f];
        const float4 v = *(const float4*)(atom_emb + ((size_t)(f * 64 + idx) * DD) + lane * 4);
        a0 += v.x; a1 += v.y; a2 += v.z; a3 += v.w;
    }
    ushort4 o;
    o.x = f2h_bits(a0); o.y = f2h_bits(a1); o.z = f2h_bits(a2); o.w = f2h_bits(a3);
    *(ushort4*)(h + (size_t)n * DD + lane * 4) = o;
}

// ---------------- edge aggregate (fp16 h, fp16 bsum) → A fp16 ----------------
// A = fp16( (1+eps)*h + sum_{e: dst=n} relu(h[src]+bsum[cid])*w )

__global__ void agg_kernel(const unsigned short* __restrict__ h, const int* __restrict__ row_ptr,
                           const uint2* __restrict__ edata, const unsigned short* __restrict__ bsum_l,
                           const float* __restrict__ eps_ptr, unsigned short* __restrict__ Aout) {
    int n = blockIdx.x * 8 + (threadIdx.x >> 5);
    int lane = threadIdx.x & 31;
    int beg = row_ptr[n], end = row_ptr[n + 1];
    float a0 = 0.f, a1 = 0.f, a2 = 0.f, a3 = 0.f;
    int i = beg;
    for (; i + 2 <= end; i += 2) {
        uint2 e0 = edata[i], e1 = edata[i + 1];
        uint2 h0 = *(const uint2*)(h + (size_t)e0.x * DD + lane * 4);
        uint2 b0 = *(const uint2*)(bsum_l + (size_t)(e0.y & 0xffff) * DD + lane * 4);
        uint2 h1 = *(const uint2*)(h + (size_t)e1.x * DD + lane * 4);
        uint2 b1 = *(const uint2*)(bsum_l + (size_t)(e1.y & 0xffff) * DD + lane * 4);
        float w0 = h2f((unsigned short)(e0.y >> 16));
        float w1 = h2f((unsigned short)(e1.y >> 16));
        a0 += fmaxf(h2f((unsigned short)(h0.x & 0xffff)) + h2f((unsigned short)(b0.x & 0xffff)), 0.f) * w0;
        a1 += fmaxf(h2f((unsigned short)(h0.x >> 16)) + h2f((unsigned short)(b0.x >> 16)), 0.f) * w0;
        a2 += fmaxf(h2f((unsigned short)(h0.y & 0xffff)) + h2f((unsigned short)(b0.y & 0xffff)), 0.f) * w0;
        a3 += fmaxf(h2f((unsigned short)(h0.y >> 16)) + h2f((unsigned short)(b0.y >> 16)), 0.f) * w0;
        a0 += fmaxf(h2f((unsigned short)(h1.x & 0xffff)) + h2f((unsigned short)(b1.x & 0xffff)), 0.f) * w1;
        a1 += fmaxf(h2f((unsigned short)(h1.x >> 16)) + h2f((unsigned short)(b1.x >> 16)), 0.f) * w1;
        a2 += fmaxf(h2f((unsigned short)(h1.y & 0xffff)) + h2f((unsigned short)(b1.y & 0xffff)), 0.f) * w1;
        a3 += fmaxf(h2f((unsigned short)(h1.y >> 16)) + h2f((unsigned short)(b1.y >> 16)), 0.f) * w1;
    }
    if (i < end) {
        uint2 e0 = edata[i];
        uint2 h0 = *(const uint2*)(h + (size_t)e0.x * DD + lane * 4);
        uint2 b0 = *(const uint2*)(bsum_l + (size_t)(e0.y & 0xffff) * DD + lane * 4);
        float w0 = h2f((unsigned short)(e0.y >> 16));
        a0 += fmaxf(h2f((unsigned short)(h0.x & 0xffff)) + h2f((unsigned short)(b0.x & 0xffff)), 0.f) * w0;
        a1 += fmaxf(h2f((unsigned short)(h0.x >> 16)) + h2f((unsigned short)(b0.x >> 16)), 0.f) * w0;
        a2 += fmaxf(h2f((unsigned short)(h0.y & 0xffff)) + h2f((unsigned short)(b0.y & 0xffff)), 0.f) * w0;
        a3 += fmaxf(h2f((unsigned short)(h0.y >> 16)) + h2f((unsigned short)(b0.y >> 16)), 0.f) * w0;
    }
    float eps1 = 1.f + eps_ptr[0];
    uint2 hs = *(const uint2*)(h + (size_t)n * DD + lane * 4);
    ushort4 o;
    o.x = f2h_bits(eps1 * h2f((unsigned short)(hs.x & 0xffff)) + a0);
    o.y = f2h_bits(eps1 * h2f((unsigned short)(hs.x >> 16)) + a1);
    o.z = f2h_bits(eps1 * h2f((unsigned short)(hs.y & 0xffff)) + a2);
    o.w = f2h_bits(eps1 * h2f((unsigned short)(hs.y >> 16)) + a3);
    *(ushort4*)(Aout + (size_t)n * DD + lane * 4) = o;
}

// ---------------- fp16 MFMA GEMM, reg-resident B + full A prefetch, fp16 out ----------------
// C(NN x M) = A(NN x K) @ Bt^T + bias. Partial col stats -> pstats (non-atomic).

template <int K, int M>
__global__ __launch_bounds__(256, (K == 128) ? 4 : 3) void mfma_gemm_kernel(
    const unsigned short* __restrict__ A, const unsigned short* __restrict__ Bt,
    const float* __restrict__ bias, unsigned short* __restrict__ C,
    float* __restrict__ pstats) {
    const int KS = K / 32;
    int wave = threadIdx.x >> 6;
    int lane = threadIdx.x & 63;
    int wr = wave >> 1, wc = wave & 1;
    int row0 = blockIdx.x * 64 + wr * 32;
    int col0 = blockIdx.y * 64 + wc * 32;
    int lr = lane & 15;
    int q = lane >> 4;

    half8 b[2][KS];
#pragma unroll
    for (int j = 0; j < 2; j++) {
        const unsigned short* bp = Bt + (size_t)(col0 + j * 16 + lr) * K + q * 8;
#pragma unroll
        for (int ks = 0; ks < KS; ks++)
            b[j][ks] = __builtin_bit_cast(half8, *(const int4*)(bp + ks * 32));
    }
    half8 a[2][KS];
#pragma unroll
    for (int i = 0; i < 2; i++) {
        int row = row0 + i * 16 + lr;
        const unsigned short* ap = A + (size_t)row * K + q * 8;
#pragma unroll
        for (int ks = 0; ks < KS; ks++) {
            int4 t = {0, 0, 0, 0};
            if (row < NN) t = *(const int4*)(ap + ks * 32);
            a[i][ks] = __builtin_bit_cast(half8, t);
        }
    }

    f32x4 acc[2][2];
#pragma unroll
    for (int i = 0; i < 2; i++)
#pragma unroll
        for (int j = 0; j < 2; j++) acc[i][j] = (f32x4){0.f, 0.f, 0.f, 0.f};

#pragma unroll
    for (int ks = 0; ks < KS; ks++)
#pragma unroll
        for (int i = 0; i < 2; i++)
#pragma unroll
            for (int j = 0; j < 2; j++)
                acc[i][j] = __builtin_amdgcn_mfma_f32_16x16x32_f16(a[i][ks], b[j][ks], acc[i][j], 0, 0, 0);

    int NR = 2 * gridDim.x;
    int rb = blockIdx.x * 2 + wr;
#pragma unroll
    for (int j = 0; j < 2; j++) {
        int c = col0 + j * 16 + lr;
        float bi = bias[c];
        float s = 0.f, sq = 0.f;
#pragma unroll
        for (int i = 0; i < 2; i++) {
#pragma unroll
            for (int r = 0; r < 4; r++) {
                int row = row0 + i * 16 + q * 4 + r;
                float v = 0.f;
                if (row < NN) {
                    v = acc[i][j][r] + bi;
                    C[(size_t)row * M + c] = f2h_bits(v);
                }
                s += v;
                sq += v * v;
            }
        }
        s += __shfl_xor(s, 16);
        s += __shfl_xor(s, 32);
        sq += __shfl_xor(sq, 16);
        sq += __shfl_xor(sq, 32);
        if (q == 0) {
            pstats[(size_t)rb * M + c] = s;
            pstats[((size_t)NR + rb) * M + c] = sq;
        }
    }
}

// ---------------- stats reduce: pstats[NR][M] -> stats2[16][M] (non-atomic) ----------------

__global__ void reduce_stats_kernel(const float* __restrict__ pstats, float* __restrict__ stats2,
                                    int M, int NR) {
    int c = threadIdx.x;  // blockDim.x == M
    int r = blockIdx.x;   // 8 blocks
    int chunk = (NR + 7) / 8;
    int r0 = r * chunk;
    int r1 = r0 + chunk;
    if (r1 > NR) r1 = NR;
    float s = 0.f, q = 0.f;
    for (int i = r0; i < r1; i++) {
        s += pstats[(size_t)i * M + c];
        q += pstats[((size_t)NR + i) * M + c];
    }
    stats2[r * M + c] = s;
    stats2[(8 + r) * M + c] = q;
}

// ---------------- BN apply 1 (finalize fused): z1 fp16 -> fp16 relu, M=256, 8/thread --------

__global__ void bnapply1_kernel(const unsigned short* __restrict__ z,
                                const float* __restrict__ stats2, const float* __restrict__ g,
                                const float* __restrict__ bb, unsigned short* __restrict__ o) {
    __shared__ float s_sh[DD2], t_sh[DD2];
    {
        int c = threadIdx.x;
        float s = 0.f, q = 0.f;
#pragma unroll
        for (int r = 0; r < 8; r++) {
            s += stats2[r * DD2 + c];
            q += stats2[(8 + r) * DD2 + c];
        }
        float mean = s * (1.f / NN);
        float var = q * (1.f / NN) - mean * mean;
        float sc = g[c] * rsqrtf(var + BN_EPS);
        s_sh[c] = sc;
        t_sh[c] = bb[c] - mean * sc;
    }
    __syncthreads();
    int i = (blockIdx.x * 256 + threadIdx.x) * 8;
    int c0 = i & 255;
    uint4 in = *(const uint4*)(z + i);
    unsigned int w[4] = {in.x, in.y, in.z, in.w};
    uint4 out;
    unsigned int* po = (unsigned int*)&out;
#pragma unroll
    for (int k = 0; k < 4; k++) {
        int c = c0 + 2 * k;
        float v0 = fmaxf(h2f((unsigned short)(w[k] & 0xffff)) * s_sh[c] + t_sh[c], 0.f);
        float v1 = fmaxf(h2f((unsigned short)(w[k] >> 16)) * s_sh[c + 1] + t_sh[c + 1], 0.f);
        po[k] = (unsigned int)f2h_bits(v0) | ((unsigned int)f2h_bits(v1) << 16);
    }
    *(uint4*)(o + i) = out;
}

// ---------------- BN apply 2 (finalize fused): z2 fp16 -> h fp16 (relu) or d_out fp32 -------

__global__ void bnapply2_kernel(const unsigned short* __restrict__ z,
                                const float* __restrict__ stats2, const float* __restrict__ g,
                                const float* __restrict__ bb, unsigned short* __restrict__ hout,
                                float* __restrict__ fout, int last) {
    __shared__ float s_sh[DD], t_sh[DD];
    if (threadIdx.x < DD) {
        int c = threadIdx.x;
        float s = 0.f, q = 0.f;
#pragma unroll
        for (int r = 0; r < 8; r++) {
            s += stats2[r * DD + c];
            q += stats2[(8 + r) * DD + c];
        }
        float mean = s * (1.f / NN);
        float var = q * (1.f / NN) - mean * mean;
        float sc = g[c] * rsqrtf(var + BN_EPS);
        s_sh[c] = sc;
        t_sh[c] = bb[c] - mean * sc;
    }
    __syncthreads();
    int i = (blockIdx.x * 256 + threadIdx.x) * 4;
    int c = i & 127;
    uint2 in = *(const uint2*)(z + i);
    float v0 = h2f((unsigned short)(in.x & 0xffff)) * s_sh[c] + t_sh[c];
    float v1 = h2f((unsigned short)(in.x >> 16)) * s_sh[c + 1] + t_sh[c + 1];
    float v2 = h2f((unsigned short)(in.y & 0xffff)) * s_sh[c + 2] + t_sh[c + 2];
    float v3 = h2f((unsigned short)(in.y >> 16)) * s_sh[c + 3] + t_sh[c + 3];
    if (last) {
        float4 out; out.x = v0; out.y = v1; out.z = v2; out.w = v3;
        *(float4*)(fout + i) = out;
    } else {
        ushort4 out;
        out.x = f2h_bits(fmaxf(v0, 0.f));
        out.y = f2h_bits(fmaxf(v1, 0.f));
        out.z = f2h_bits(fmaxf(v2, 0.f));
        out.w = f2h_bits(fmaxf(v3, 0.f));
        *(ushort4*)(hout + i) = out;
    }
}

// ---------------- launch ----------------

extern "C" void kernel_launch(void* const* d_in, const int* in_sizes, int n_in,
                              void* d_out, int out_size, void* d_ws, size_t ws_size,
                              hipStream_t stream) {
    const int* x = (const int*)d_in[0];
    const int* edge_index = (const int*)d_in[1];
    const int* edge_attr = (const int*)d_in[2];
    const float* edge_weight = (const float*)d_in[3];
    const float* atom_emb = (const float*)d_in[4];
    const float* bond_emb = (const float*)d_in[5];
    const float* W1 = (const float*)d_in[6];
    const float* b1 = (const float*)d_in[7];
    const float* bn1_g = (const float*)d_in[8];
    const float* bn1_b = (const float*)d_in[9];
    const float* W2 = (const float*)d_in[10];
    const float* b2 = (const float*)d_in[11];
    const float* eps_p = (const float*)d_in[12];
    const float* bn_g = (const float*)d_in[13];
    const float* bn_b = (const float*)d_in[14];
    const int* srcv = edge_index;
    const int* dstv = edge_index + EE;

    char* p = (char*)d_ws;
    auto alloc = [&](size_t bytes) {
        void* r = (void*)p;
        p += (bytes + 255) & ~(size_t)255;
        return r;
    };
    unsigned short* h = (unsigned short*)alloc((size_t)NN * DD * 2);     // fp16 node state
    unsigned short* A1h = (unsigned short*)alloc((size_t)NN * DD * 2);   // agg out fp16
    unsigned short* z1 = (unsigned short*)alloc((size_t)NN * DD2 * 2);   // gemm1 out fp16
    unsigned short* z1h = (unsigned short*)alloc((size_t)NN * DD2 * 2);  // bn1+relu fp16
    unsigned short* z2 = (unsigned short*)alloc((size_t)NN * DD * 2);    // gemm2 out fp16
    uint2* edata = (uint2*)alloc((size_t)EE * 8);
    int* counts = (int*)alloc((size_t)NN * 4);
    int* row_ptr = (int*)alloc((size_t)(NN + 1) * 4);
    int* blksum = (int*)alloc(256 * 4);
    unsigned short* W1t = (unsigned short*)alloc((size_t)LL * DD * DD2 * 2);
    unsigned short* W2t = (unsigned short*)alloc((size_t)LL * DD * DD2 * 2);
    unsigned short* bsum = (unsigned short*)alloc((size_t)LL * 512 * DD * 2);
    float* pstats = (float*)alloc((size_t)2 * 1564 * 256 * 4);
    float* stats2a = (float*)alloc(16 * DD2 * 4);
    float* stats2b = (float*)alloc(16 * DD * 4);

    const int GR = (NN + 63) / 64;  // 782
    const int NR = 2 * GR;          // 1564

    // --- one-time prep ---
    hipMemsetAsync(counts, 0, (size_t)NN * 4, stream);
    hist_kernel<<<(EE + 255) / 256, 256, 0, stream>>>(dstv, counts);
    int nblk = (NN + 255) / 256;
    scan1_kernel<<<nblk, 256, 0, stream>>>(counts, row_ptr, blksum);
    scan2_kernel<<<1, 256, 0, stream>>>(blksum, nblk);
    scan3_kernel<<<nblk, 256, 0, stream>>>(row_ptr, blksum);
    hipMemsetAsync(counts, 0, (size_t)NN * 4, stream);
    scatter_kernel<<<(EE + 255) / 256, 256, 0, stream>>>(dstv, srcv, edge_attr, edge_weight,
                                                         row_ptr, counts, edata);
    prep_tables_kernel<<<(2 * LL * DD * DD2 + LL * 512 * DD + 255) / 256, 256, 0, stream>>>(
        W1, W2, bond_emb, W1t, W2t, bsum);
    init_h_kernel<<<NN / 8, 256, 0, stream>>>(x, atom_emb, h);

    for (int l = 0; l < LL; l++) {
        agg_kernel<<<NN / 8, 256, 0, stream>>>(h, row_ptr, edata, bsum + (size_t)l * 512 * DD,
                                               eps_p + l, A1h);

        mfma_gemm_kernel<DD, DD2><<<dim3(GR, DD2 / 64), 256, 0, stream>>>(
            A1h, W1t + (size_t)l * DD * DD2, b1 + l * DD2, z1, pstats);
        reduce_stats_kernel<<<8, DD2, 0, stream>>>(pstats, stats2a, DD2, NR);
        bnapply1_kernel<<<NN * DD2 / 2048, 256, 0, stream>>>(z1, stats2a, bn1_g + l * DD2,
                                                             bn1_b + l * DD2, z1h);

        mfma_gemm_kernel<DD2, DD><<<dim3(GR, DD / 64), 256, 0, stream>>>(
            z1h, W2t + (size_t)l * DD * DD2, b2 + l * DD, z2, pstats);
        reduce_stats_kernel<<<8, DD, 0, stream>>>(pstats, stats2b, DD, NR);
        bnapply2_kernel<<<NN * DD / 1024, 256, 0, stream>>>(z2, stats2b, bn_g + l * DD,
                                                            bn_b + l * DD, h, (float*)d_out,
                                                            (l == LL - 1) ? 1 : 0);
    }
}

// Round 6
// 713.209 us; speedup vs baseline: 2.1203x; 1.8745x over previous
//
#include <hip/hip_runtime.h>

#define NN 50000
#define EE 600000
#define DD 128
#define DD2 256
#define LL 5
#define BN_EPS 1e-5f

typedef __attribute__((ext_vector_type(8))) _Float16 half8;
typedef __attribute__((ext_vector_type(4))) float f32x4;

__device__ inline unsigned short f2h_bits(float f) {
    _Float16 h = (_Float16)f;  // RTNE
    return __builtin_bit_cast(unsigned short, h);
}
__device__ inline float h2f(unsigned short u) {
    return (float)__builtin_bit_cast(_Float16, u);
}

// ---------------- CSR build ----------------

__global__ void hist_kernel(const int* __restrict__ dst, int* __restrict__ counts) {
    int e = blockIdx.x * blockDim.x + threadIdx.x;
    if (e < EE) atomicAdd(&counts[dst[e]], 1);
}

__global__ void scan1_kernel(const int* __restrict__ counts, int* __restrict__ row_ptr,
                             int* __restrict__ blksum) {
    __shared__ int tmp[256];
    int i = blockIdx.x * 256 + threadIdx.x;
    int v = (i < NN) ? counts[i] : 0;
    tmp[threadIdx.x] = v;
    __syncthreads();
    for (int off = 1; off < 256; off <<= 1) {
        int x = 0;
        if (threadIdx.x >= off) x = tmp[threadIdx.x - off];
        __syncthreads();
        if (threadIdx.x >= off) tmp[threadIdx.x] += x;
        __syncthreads();
    }
    if (i < NN) row_ptr[i] = tmp[threadIdx.x] - v;
    if (threadIdx.x == 255) blksum[blockIdx.x] = tmp[255];
}

__global__ void scan2_kernel(int* __restrict__ blksum, int nblocks) {
    __shared__ int tmp[256];
    int v = (threadIdx.x < nblocks) ? blksum[threadIdx.x] : 0;
    tmp[threadIdx.x] = v;
    __syncthreads();
    for (int off = 1; off < 256; off <<= 1) {
        int x = 0;
        if (threadIdx.x >= off) x = tmp[threadIdx.x - off];
        __syncthreads();
        if (threadIdx.x >= off) tmp[threadIdx.x] += x;
        __syncthreads();
    }
    blksum[threadIdx.x] = tmp[threadIdx.x] - v;
}

__global__ void scan3_kernel(int* __restrict__ row_ptr, const int* __restrict__ blksum) {
    int i = blockIdx.x * 256 + threadIdx.x;
    if (i < NN) row_ptr[i] += blksum[blockIdx.x];
    if (i == 0) row_ptr[NN] = EE;
}

// scatter + pack edge data: edata[p] = {src, cid | w_fp16<<16}, cid = a0 + 8*a1 + 64*a2
__global__ void scatter_kernel(const int* __restrict__ dst, const int* __restrict__ src,
                               const int* __restrict__ edge_attr, const float* __restrict__ ew,
                               const int* __restrict__ row_ptr, int* __restrict__ cursor,
                               uint2* __restrict__ edata) {
    int e = blockIdx.x * blockDim.x + threadIdx.x;
    if (e < EE) {
        int d = dst[e];
        int p = row_ptr[d] + atomicAdd(&cursor[d], 1);
        int cid = edge_attr[3 * e + 0] + 8 * edge_attr[3 * e + 1] + 64 * edge_attr[3 * e + 2];
        uint2 v;
        v.x = (unsigned)src[e];
        v.y = (unsigned)cid | ((unsigned)f2h_bits(ew[e]) << 16);
        edata[p] = v;
    }
}

// ---------------- table prep: W1t, W2t (fp16, [M][K]) + combined bond table (fp16) ------------

__global__ void prep_tables_kernel(const float* __restrict__ W1, const float* __restrict__ W2,
                                   const float* __restrict__ bond_emb,
                                   unsigned short* __restrict__ W1t,
                                   unsigned short* __restrict__ W2t,
                                   unsigned short* __restrict__ bsum) {
    const int NW = LL * DD * DD2;  // 163840
    int idx = blockIdx.x * 256 + threadIdx.x;
    if (idx < NW) {
        int l = idx / (DD * DD2);
        int rem = idx - l * DD * DD2;
        int k = rem / DD2, m = rem - k * DD2;  // W1: [L][128][256]
        W1t[(size_t)l * DD * DD2 + (size_t)m * DD + k] = f2h_bits(W1[idx]);
    } else if (idx < 2 * NW) {
        int j = idx - NW;
        int l = j / (DD * DD2);
        int rem = j - l * DD * DD2;
        int k = rem / DD, m = rem - k * DD;  // W2: [L][256][128]
        W2t[(size_t)l * DD * DD2 + (size_t)m * DD2 + k] = f2h_bits(W2[j]);
    } else if (idx < 2 * NW + LL * 512 * DD) {
        int j = idx - 2 * NW;
        int l = j >> 16;  // 512*128 = 65536
        int rem = j & 65535;
        int cid = rem >> 7, d = rem & 127;
        int a0 = cid & 7, a1 = (cid >> 3) & 7, a2 = cid >> 6;
        const float* base = bond_emb + (size_t)l * 3 * 8 * DD;
        bsum[j] = f2h_bits(base[a0 * DD + d] + base[(8 + a1) * DD + d] + base[(16 + a2) * DD + d]);
    }
}

// ---------------- node init (fp16 h) ----------------

__global__ void init_h_kernel(const int* __restrict__ x, const float* __restrict__ atom_emb,
                              unsigned short* __restrict__ h) {
    int n = blockIdx.x * 8 + (threadIdx.x >> 5);
    int lane = threadIdx.x & 31;
    float a0 = 0.f, a1 = 0.f, a2 = 0.f, a3 = 0.f;
#pragma unroll
    for (int f = 0; f < 9; f++) {
        int idx = x[n * 9 + f];
        const float4 v = *(const float4*)(atom_emb + ((size_t)(f * 64 + idx) * DD) + lane * 4);
        a0 += v.x; a1 += v.y; a2 += v.z; a3 += v.w;
    }
    ushort4 o;
    o.x = f2h_bits(a0); o.y = f2h_bits(a1); o.z = f2h_bits(a2); o.w = f2h_bits(a3);
    *(ushort4*)(h + (size_t)n * DD + lane * 4) = o;
}

// ---------------- edge aggregate (fp16 h, fp16 bsum) → A fp16 ----------------

__global__ void agg_kernel(const unsigned short* __restrict__ h, const int* __restrict__ row_ptr,
                           const uint2* __restrict__ edata, const unsigned short* __restrict__ bsum_l,
                           const float* __restrict__ eps_ptr, unsigned short* __restrict__ Aout) {
    int n = blockIdx.x * 8 + (threadIdx.x >> 5);
    int lane = threadIdx.x & 31;
    int beg = row_ptr[n], end = row_ptr[n + 1];
    float a0 = 0.f, a1 = 0.f, a2 = 0.f, a3 = 0.f;
    int i = beg;
    for (; i + 2 <= end; i += 2) {
        uint2 e0 = edata[i], e1 = edata[i + 1];
        uint2 h0 = *(const uint2*)(h + (size_t)e0.x * DD + lane * 4);
        uint2 b0 = *(const uint2*)(bsum_l + (size_t)(e0.y & 0xffff) * DD + lane * 4);
        uint2 h1 = *(const uint2*)(h + (size_t)e1.x * DD + lane * 4);
        uint2 b1 = *(const uint2*)(bsum_l + (size_t)(e1.y & 0xffff) * DD + lane * 4);
        float w0 = h2f((unsigned short)(e0.y >> 16));
        float w1 = h2f((unsigned short)(e1.y >> 16));
        a0 += fmaxf(h2f((unsigned short)(h0.x & 0xffff)) + h2f((unsigned short)(b0.x & 0xffff)), 0.f) * w0;
        a1 += fmaxf(h2f((unsigned short)(h0.x >> 16)) + h2f((unsigned short)(b0.x >> 16)), 0.f) * w0;
        a2 += fmaxf(h2f((unsigned short)(h0.y & 0xffff)) + h2f((unsigned short)(b0.y & 0xffff)), 0.f) * w0;
        a3 += fmaxf(h2f((unsigned short)(h0.y >> 16)) + h2f((unsigned short)(b0.y >> 16)), 0.f) * w0;
        a0 += fmaxf(h2f((unsigned short)(h1.x & 0xffff)) + h2f((unsigned short)(b1.x & 0xffff)), 0.f) * w1;
        a1 += fmaxf(h2f((unsigned short)(h1.x >> 16)) + h2f((unsigned short)(b1.x >> 16)), 0.f) * w1;
        a2 += fmaxf(h2f((unsigned short)(h1.y & 0xffff)) + h2f((unsigned short)(b1.y & 0xffff)), 0.f) * w1;
        a3 += fmaxf(h2f((unsigned short)(h1.y >> 16)) + h2f((unsigned short)(b1.y >> 16)), 0.f) * w1;
    }
    if (i < end) {
        uint2 e0 = edata[i];
        uint2 h0 = *(const uint2*)(h + (size_t)e0.x * DD + lane * 4);
        uint2 b0 = *(const uint2*)(bsum_l + (size_t)(e0.y & 0xffff) * DD + lane * 4);
        float w0 = h2f((unsigned short)(e0.y >> 16));
        a0 += fmaxf(h2f((unsigned short)(h0.x & 0xffff)) + h2f((unsigned short)(b0.x & 0xffff)), 0.f) * w0;
        a1 += fmaxf(h2f((unsigned short)(h0.x >> 16)) + h2f((unsigned short)(b0.x >> 16)), 0.f) * w0;
        a2 += fmaxf(h2f((unsigned short)(h0.y & 0xffff)) + h2f((unsigned short)(b0.y & 0xffff)), 0.f) * w0;
        a3 += fmaxf(h2f((unsigned short)(h0.y >> 16)) + h2f((unsigned short)(b0.y >> 16)), 0.f) * w0;
    }
    float eps1 = 1.f + eps_ptr[0];
    uint2 hs = *(const uint2*)(h + (size_t)n * DD + lane * 4);
    ushort4 o;
    o.x = f2h_bits(eps1 * h2f((unsigned short)(hs.x & 0xffff)) + a0);
    o.y = f2h_bits(eps1 * h2f((unsigned short)(hs.x >> 16)) + a1);
    o.z = f2h_bits(eps1 * h2f((unsigned short)(hs.y & 0xffff)) + a2);
    o.w = f2h_bits(eps1 * h2f((unsigned short)(hs.y >> 16)) + a3);
    *(ushort4*)(Aout + (size_t)n * DD + lane * 4) = o;
}

// ---------------- persistent fp16 MFMA GEMM, reg-resident B, reg-accumulated stats -----------
// C(NN x M) = A(NN x K) @ Bt^T + bias, fp16 out. Each block loops row-tiles rb = bx, bx+GX,...
// Stats partials: pstats[(bx*2+wr)*M + c] (sum) / [(NR + bx*2+wr)*M + c] (sumsq), NR = 2*GX.

template <int K, int M, int GX>
__global__ __launch_bounds__(256, 2) void mfma_gemm_persist(
    const unsigned short* __restrict__ A, const unsigned short* __restrict__ Bt,
    const float* __restrict__ bias, unsigned short* __restrict__ C,
    float* __restrict__ pstats) {
    const int KS = K / 32;
    const int GR = (NN + 63) / 64;  // 782
    int wave = threadIdx.x >> 6;
    int lane = threadIdx.x & 63;
    int wr = wave >> 1, wc = wave & 1;
    int col0 = blockIdx.y * 64 + wc * 32;
    int lr = lane & 15;
    int q = lane >> 4;

    // B stripe: loaded once per block, lives in registers for all row-tiles
    half8 b[2][KS];
#pragma unroll
    for (int j = 0; j < 2; j++) {
        const unsigned short* bp = Bt + (size_t)(col0 + j * 16 + lr) * K + q * 8;
#pragma unroll
        for (int ks = 0; ks < KS; ks++)
            b[j][ks] = __builtin_bit_cast(half8, *(const int4*)(bp + ks * 32));
    }

    float bi[2];
#pragma unroll
    for (int j = 0; j < 2; j++) bi[j] = bias[col0 + j * 16 + lr];

    float s_acc[2] = {0.f, 0.f}, sq_acc[2] = {0.f, 0.f};

    for (int rb = blockIdx.x; rb < GR; rb += GX) {
        int row0 = rb * 64 + wr * 32;
        half8 a[2][KS];
#pragma unroll
        for (int i = 0; i < 2; i++) {
            int row = row0 + i * 16 + lr;
            const unsigned short* ap = A + (size_t)row * K + q * 8;
#pragma unroll
            for (int ks = 0; ks < KS; ks++) {
                int4 t = {0, 0, 0, 0};
                if (row < NN) t = *(const int4*)(ap + ks * 32);
                a[i][ks] = __builtin_bit_cast(half8, t);
            }
        }

        f32x4 acc[2][2];
#pragma unroll
        for (int i = 0; i < 2; i++)
#pragma unroll
            for (int j = 0; j < 2; j++) acc[i][j] = (f32x4){0.f, 0.f, 0.f, 0.f};

#pragma unroll
        for (int ks = 0; ks < KS; ks++)
#pragma unroll
            for (int i = 0; i < 2; i++)
#pragma unroll
                for (int j = 0; j < 2; j++)
                    acc[i][j] = __builtin_amdgcn_mfma_f32_16x16x32_f16(a[i][ks], b[j][ks], acc[i][j], 0, 0, 0);

#pragma unroll
        for (int j = 0; j < 2; j++) {
            int c = col0 + j * 16 + lr;
#pragma unroll
            for (int i = 0; i < 2; i++) {
#pragma unroll
                for (int r = 0; r < 4; r++) {
                    int row = row0 + i * 16 + q * 4 + r;
                    if (row < NN) {
                        float v = acc[i][j][r] + bi[j];
                        C[(size_t)row * M + c] = f2h_bits(v);
                        s_acc[j] += v;
                        sq_acc[j] += v * v;
                    }
                }
            }
        }
    }

    // one shuffle-reduce + partial write per block
    const int NR = 2 * GX;
    int rbo = blockIdx.x * 2 + wr;
#pragma unroll
    for (int j = 0; j < 2; j++) {
        int c = col0 + j * 16 + lr;
        float s = s_acc[j], sq = sq_acc[j];
        s += __shfl_xor(s, 16);
        s += __shfl_xor(s, 32);
        sq += __shfl_xor(sq, 16);
        sq += __shfl_xor(sq, 32);
        if (q == 0) {
            pstats[(size_t)rbo * M + c] = s;
            pstats[((size_t)NR + rbo) * M + c] = sq;
        }
    }
}

// ---------------- stats reduce: pstats[NR][M] -> stats2[16][M], 4-way MLP unroll -------------

__global__ void reduce_stats_kernel(const float* __restrict__ pstats, float* __restrict__ stats2,
                                    int M, int NR) {
    int c = threadIdx.x;  // blockDim.x == M
    int r = blockIdx.x;   // 16 blocks
    int chunk = NR / 16;  // 16 or 32, divisible by 4
    int r0 = r * chunk;
    float s0 = 0.f, s1 = 0.f, s2 = 0.f, s3 = 0.f;
    float q0 = 0.f, q1 = 0.f, q2 = 0.f, q3 = 0.f;
    for (int i = r0; i < r0 + chunk; i += 4) {
        s0 += pstats[(size_t)(i + 0) * M + c];
        s1 += pstats[(size_t)(i + 1) * M + c];
        s2 += pstats[(size_t)(i + 2) * M + c];
        s3 += pstats[(size_t)(i + 3) * M + c];
        q0 += pstats[((size_t)NR + i + 0) * M + c];
        q1 += pstats[((size_t)NR + i + 1) * M + c];
        q2 += pstats[((size_t)NR + i + 2) * M + c];
        q3 += pstats[((size_t)NR + i + 3) * M + c];
    }
    stats2[r * M + c] = (s0 + s1) + (s2 + s3);
    stats2[(16 + r) * M + c] = (q0 + q1) + (q2 + q3);
}

// ---------------- BN apply 1 (finalize fused): z1 fp16 -> fp16 relu, M=256, 8/thread --------

__global__ void bnapply1_kernel(const unsigned short* __restrict__ z,
                                const float* __restrict__ stats2, const float* __restrict__ g,
                                const float* __restrict__ bb, unsigned short* __restrict__ o) {
    __shared__ float s_sh[DD2], t_sh[DD2];
    {
        int c = threadIdx.x;
        float s = 0.f, q = 0.f;
#pragma unroll
        for (int r = 0; r < 16; r++) {
            s += stats2[r * DD2 + c];
            q += stats2[(16 + r) * DD2 + c];
        }
        float mean = s * (1.f / NN);
        float var = q * (1.f / NN) - mean * mean;
        float sc = g[c] * rsqrtf(var + BN_EPS);
        s_sh[c] = sc;
        t_sh[c] = bb[c] - mean * sc;
    }
    __syncthreads();
    int i = (blockIdx.x * 256 + threadIdx.x) * 8;
    int c0 = i & 255;
    uint4 in = *(const uint4*)(z + i);
    unsigned int w[4] = {in.x, in.y, in.z, in.w};
    uint4 out;
    unsigned int* po = (unsigned int*)&out;
#pragma unroll
    for (int k = 0; k < 4; k++) {
        int c = c0 + 2 * k;
        float v0 = fmaxf(h2f((unsigned short)(w[k] & 0xffff)) * s_sh[c] + t_sh[c], 0.f);
        float v1 = fmaxf(h2f((unsigned short)(w[k] >> 16)) * s_sh[c + 1] + t_sh[c + 1], 0.f);
        po[k] = (unsigned int)f2h_bits(v0) | ((unsigned int)f2h_bits(v1) << 16);
    }
    *(uint4*)(o + i) = out;
}

// ---------------- BN apply 2 (finalize fused): z2 fp16 -> h fp16 (relu) or d_out fp32 -------

__global__ void bnapply2_kernel(const unsigned short* __restrict__ z,
                                const float* __restrict__ stats2, const float* __restrict__ g,
                                const float* __restrict__ bb, unsigned short* __restrict__ hout,
                                float* __restrict__ fout, int last) {
    __shared__ float s_sh[DD], t_sh[DD];
    if (threadIdx.x < DD) {
        int c = threadIdx.x;
        float s = 0.f, q = 0.f;
#pragma unroll
        for (int r = 0; r < 16; r++) {
            s += stats2[r * DD + c];
            q += stats2[(16 + r) * DD + c];
        }
        float mean = s * (1.f / NN);
        float var = q * (1.f / NN) - mean * mean;
        float sc = g[c] * rsqrtf(var + BN_EPS);
        s_sh[c] = sc;
        t_sh[c] = bb[c] - mean * sc;
    }
    __syncthreads();
    int i = (blockIdx.x * 256 + threadIdx.x) * 4;
    int c = i & 127;
    uint2 in = *(const uint2*)(z + i);
    float v0 = h2f((unsigned short)(in.x & 0xffff)) * s_sh[c] + t_sh[c];
    float v1 = h2f((unsigned short)(in.x >> 16)) * s_sh[c + 1] + t_sh[c + 1];
    float v2 = h2f((unsigned short)(in.y & 0xffff)) * s_sh[c + 2] + t_sh[c + 2];
    float v3 = h2f((unsigned short)(in.y >> 16)) * s_sh[c + 3] + t_sh[c + 3];
    if (last) {
        float4 out; out.x = v0; out.y = v1; out.z = v2; out.w = v3;
        *(float4*)(fout + i) = out;
    } else {
        ushort4 out;
        out.x = f2h_bits(fmaxf(v0, 0.f));
        out.y = f2h_bits(fmaxf(v1, 0.f));
        out.z = f2h_bits(fmaxf(v2, 0.f));
        out.w = f2h_bits(fmaxf(v3, 0.f));
        *(ushort4*)(hout + i) = out;
    }
}

// ---------------- launch ----------------

extern "C" void kernel_launch(void* const* d_in, const int* in_sizes, int n_in,
                              void* d_out, int out_size, void* d_ws, size_t ws_size,
                              hipStream_t stream) {
    const int* x = (const int*)d_in[0];
    const int* edge_index = (const int*)d_in[1];
    const int* edge_attr = (const int*)d_in[2];
    const float* edge_weight = (const float*)d_in[3];
    const float* atom_emb = (const float*)d_in[4];
    const float* bond_emb = (const float*)d_in[5];
    const float* W1 = (const float*)d_in[6];
    const float* b1 = (const float*)d_in[7];
    const float* bn1_g = (const float*)d_in[8];
    const float* bn1_b = (const float*)d_in[9];
    const float* W2 = (const float*)d_in[10];
    const float* b2 = (const float*)d_in[11];
    const float* eps_p = (const float*)d_in[12];
    const float* bn_g = (const float*)d_in[13];
    const float* bn_b = (const float*)d_in[14];
    const int* srcv = edge_index;
    const int* dstv = edge_index + EE;

    char* p = (char*)d_ws;
    auto alloc = [&](size_t bytes) {
        void* r = (void*)p;
        p += (bytes + 255) & ~(size_t)255;
        return r;
    };
    unsigned short* h = (unsigned short*)alloc((size_t)NN * DD * 2);
    unsigned short* A1h = (unsigned short*)alloc((size_t)NN * DD * 2);
    unsigned short* z1 = (unsigned short*)alloc((size_t)NN * DD2 * 2);
    unsigned short* z1h = (unsigned short*)alloc((size_t)NN * DD2 * 2);
    unsigned short* z2 = (unsigned short*)alloc((size_t)NN * DD * 2);
    uint2* edata = (uint2*)alloc((size_t)EE * 8);
    int* counts = (int*)alloc((size_t)NN * 4);
    int* row_ptr = (int*)alloc((size_t)(NN + 1) * 4);
    int* blksum = (int*)alloc(256 * 4);
    unsigned short* W1t = (unsigned short*)alloc((size_t)LL * DD * DD2 * 2);
    unsigned short* W2t = (unsigned short*)alloc((size_t)LL * DD * DD2 * 2);
    unsigned short* bsum = (unsigned short*)alloc((size_t)LL * 512 * DD * 2);
    float* pstats = (float*)alloc((size_t)2 * 512 * 256 * 4);  // max NR=512, M=256
    float* stats2a = (float*)alloc(32 * DD2 * 4);
    float* stats2b = (float*)alloc(32 * DD * 4);

    // --- one-time prep ---
    hipMemsetAsync(counts, 0, (size_t)NN * 4, stream);
    hist_kernel<<<(EE + 255) / 256, 256, 0, stream>>>(dstv, counts);
    int nblk = (NN + 255) / 256;
    scan1_kernel<<<nblk, 256, 0, stream>>>(counts, row_ptr, blksum);
    scan2_kernel<<<1, 256, 0, stream>>>(blksum, nblk);
    scan3_kernel<<<nblk, 256, 0, stream>>>(row_ptr, blksum);
    hipMemsetAsync(counts, 0, (size_t)NN * 4, stream);
    scatter_kernel<<<(EE + 255) / 256, 256, 0, stream>>>(dstv, srcv, edge_attr, edge_weight,
                                                         row_ptr, counts, edata);
    prep_tables_kernel<<<(2 * LL * DD * DD2 + LL * 512 * DD + 255) / 256, 256, 0, stream>>>(
        W1, W2, bond_emb, W1t, W2t, bsum);
    init_h_kernel<<<NN / 8, 256, 0, stream>>>(x, atom_emb, h);

    for (int l = 0; l < LL; l++) {
        agg_kernel<<<NN / 8, 256, 0, stream>>>(h, row_ptr, edata, bsum + (size_t)l * 512 * DD,
                                               eps_p + l, A1h);

        // GEMM1: K=128, M=256, GX=128 -> 512 blocks, NR=256
        mfma_gemm_persist<DD, DD2, 128><<<dim3(128, DD2 / 64), 256, 0, stream>>>(
            A1h, W1t + (size_t)l * DD * DD2, b1 + l * DD2, z1, pstats);
        reduce_stats_kernel<<<16, DD2, 0, stream>>>(pstats, stats2a, DD2, 256);
        bnapply1_kernel<<<NN * DD2 / 2048, 256, 0, stream>>>(z1, stats2a, bn1_g + l * DD2,
                                                             bn1_b + l * DD2, z1h);

        // GEMM2: K=256, M=128, GX=256 -> 512 blocks, NR=512
        mfma_gemm_persist<DD2, DD, 256><<<dim3(256, DD / 64), 256, 0, stream>>>(
            z1h, W2t + (size_t)l * DD * DD2, b2 + l * DD, z2, pstats);
        reduce_stats_kernel<<<16, DD, 0, stream>>>(pstats, stats2b, DD, 512);
        bnapply2_kernel<<<NN * DD / 1024, 256, 0, stream>>>(z2, stats2b, bn_g + l * DD,
                                                            bn_b + l * DD, h, (float*)d_out,
                                                            (l == LL - 1) ? 1 : 0);
    }
}

// Round 7
// 703.899 us; speedup vs baseline: 2.1483x; 1.0132x over previous
//
#include <hip/hip_runtime.h>

#define NN 50000
#define EE 600000
#define DD 128
#define DD2 256
#define LL 5
#define BN_EPS 1e-5f

typedef __attribute__((ext_vector_type(8))) _Float16 half8;
typedef __attribute__((ext_vector_type(4))) float f32x4;

__device__ inline unsigned short f2h_bits(float f) {
    _Float16 h = (_Float16)f;  // RTNE
    return __builtin_bit_cast(unsigned short, h);
}
__device__ inline float h2f(unsigned short u) {
    return (float)__builtin_bit_cast(_Float16, u);
}

// ---------------- CSR build ----------------

__global__ void hist_kernel(const int* __restrict__ dst, int* __restrict__ counts) {
    int e = blockIdx.x * blockDim.x + threadIdx.x;
    if (e < EE) atomicAdd(&counts[dst[e]], 1);
}

__global__ void scan1_kernel(const int* __restrict__ counts, int* __restrict__ row_ptr,
                             int* __restrict__ blksum) {
    __shared__ int tmp[256];
    int i = blockIdx.x * 256 + threadIdx.x;
    int v = (i < NN) ? counts[i] : 0;
    tmp[threadIdx.x] = v;
    __syncthreads();
    for (int off = 1; off < 256; off <<= 1) {
        int x = 0;
        if (threadIdx.x >= off) x = tmp[threadIdx.x - off];
        __syncthreads();
        if (threadIdx.x >= off) tmp[threadIdx.x] += x;
        __syncthreads();
    }
    if (i < NN) row_ptr[i] = tmp[threadIdx.x] - v;
    if (threadIdx.x == 255) blksum[blockIdx.x] = tmp[255];
}

__global__ void scan2_kernel(int* __restrict__ blksum, int nblocks) {
    __shared__ int tmp[256];
    int v = (threadIdx.x < nblocks) ? blksum[threadIdx.x] : 0;
    tmp[threadIdx.x] = v;
    __syncthreads();
    for (int off = 1; off < 256; off <<= 1) {
        int x = 0;
        if (threadIdx.x >= off) x = tmp[threadIdx.x - off];
        __syncthreads();
        if (threadIdx.x >= off) tmp[threadIdx.x] += x;
        __syncthreads();
    }
    blksum[threadIdx.x] = tmp[threadIdx.x] - v;
}

__global__ void scan3_kernel(int* __restrict__ row_ptr, const int* __restrict__ blksum) {
    int i = blockIdx.x * 256 + threadIdx.x;
    if (i < NN) row_ptr[i] += blksum[blockIdx.x];
    if (i == 0) row_ptr[NN] = EE;
}

// scatter + pack edge data: edata[p] = {src, cid | w_fp16<<16}, cid = a0 + 8*a1 + 64*a2
__global__ void scatter_kernel(const int* __restrict__ dst, const int* __restrict__ src,
                               const int* __restrict__ edge_attr, const float* __restrict__ ew,
                               const int* __restrict__ row_ptr, int* __restrict__ cursor,
                               uint2* __restrict__ edata) {
    int e = blockIdx.x * blockDim.x + threadIdx.x;
    if (e < EE) {
        int d = dst[e];
        int p = row_ptr[d] + atomicAdd(&cursor[d], 1);
        int cid = edge_attr[3 * e + 0] + 8 * edge_attr[3 * e + 1] + 64 * edge_attr[3 * e + 2];
        uint2 v;
        v.x = (unsigned)src[e];
        v.y = (unsigned)cid | ((unsigned)f2h_bits(ew[e]) << 16);
        edata[p] = v;
    }
}

// ---------------- table prep: W1t, W2t (fp16, [M][K]) + combined bond table (fp16) ------------

__global__ void prep_tables_kernel(const float* __restrict__ W1, const float* __restrict__ W2,
                                   const float* __restrict__ bond_emb,
                                   unsigned short* __restrict__ W1t,
                                   unsigned short* __restrict__ W2t,
                                   unsigned short* __restrict__ bsum) {
    const int NW = LL * DD * DD2;  // 163840
    int idx = blockIdx.x * 256 + threadIdx.x;
    if (idx < NW) {
        int l = idx / (DD * DD2);
        int rem = idx - l * DD * DD2;
        int k = rem / DD2, m = rem - k * DD2;  // W1: [L][128][256]
        W1t[(size_t)l * DD * DD2 + (size_t)m * DD + k] = f2h_bits(W1[idx]);
    } else if (idx < 2 * NW) {
        int j = idx - NW;
        int l = j / (DD * DD2);
        int rem = j - l * DD * DD2;
        int k = rem / DD, m = rem - k * DD;  // W2: [L][256][128]
        W2t[(size_t)l * DD * DD2 + (size_t)m * DD2 + k] = f2h_bits(W2[j]);
    } else if (idx < 2 * NW + LL * 512 * DD) {
        int j = idx - 2 * NW;
        int l = j >> 16;  // 512*128 = 65536
        int rem = j & 65535;
        int cid = rem >> 7, d = rem & 127;
        int a0 = cid & 7, a1 = (cid >> 3) & 7, a2 = cid >> 6;
        const float* base = bond_emb + (size_t)l * 3 * 8 * DD;
        bsum[j] = f2h_bits(base[a0 * DD + d] + base[(8 + a1) * DD + d] + base[(16 + a2) * DD + d]);
    }
}

// ---------------- node init (fp16 h0) ----------------

__global__ void init_h_kernel(const int* __restrict__ x, const float* __restrict__ atom_emb,
                              unsigned short* __restrict__ h) {
    int n = blockIdx.x * 8 + (threadIdx.x >> 5);
    int lane = threadIdx.x & 31;
    float a0 = 0.f, a1 = 0.f, a2 = 0.f, a3 = 0.f;
#pragma unroll
    for (int f = 0; f < 9; f++) {
        int idx = x[n * 9 + f];
        const float4 v = *(const float4*)(atom_emb + ((size_t)(f * 64 + idx) * DD) + lane * 4);
        a0 += v.x; a1 += v.y; a2 += v.z; a3 += v.w;
    }
    ushort4 o;
    o.x = f2h_bits(a0); o.y = f2h_bits(a1); o.z = f2h_bits(a2); o.w = f2h_bits(a3);
    *(ushort4*)(h + (size_t)n * DD + lane * 4) = o;
}

// ---------------- edge aggregate → A fp16, optional fused BN2+relu on gathered rows ----------
// FUSE=0: hv = hsrc (h0).  FUSE=1: hv = relu(hsrc*s + t), s/t derived from stats+g+b.
// A = fp16( (1+eps)*hv[n] + sum_{e: dst=n} relu(hv[src]+bsum[cid])*w )

template <bool FUSE>
__global__ void agg_kernel(const unsigned short* __restrict__ hsrc,
                           const float* __restrict__ stats, const float* __restrict__ g,
                           const float* __restrict__ bb, const int* __restrict__ row_ptr,
                           const uint2* __restrict__ edata,
                           const unsigned short* __restrict__ bsum_l,
                           const float* __restrict__ eps_ptr, unsigned short* __restrict__ Aout) {
    int n = blockIdx.x * 8 + (threadIdx.x >> 5);
    int lane = threadIdx.x & 31;
    int c0 = lane * 4;

    float bs[4] = {1.f, 1.f, 1.f, 1.f}, bt[4] = {0.f, 0.f, 0.f, 0.f};
    if (FUSE) {
        float4 sm = *(const float4*)(stats + c0);
        float4 sq = *(const float4*)(stats + DD + c0);
        float4 gg = *(const float4*)(g + c0);
        float4 bv = *(const float4*)(bb + c0);
        float mv[4] = {sm.x, sm.y, sm.z, sm.w};
        float qv[4] = {sq.x, sq.y, sq.z, sq.w};
        float gv[4] = {gg.x, gg.y, gg.z, gg.w};
        float bbv[4] = {bv.x, bv.y, bv.z, bv.w};
#pragma unroll
        for (int k = 0; k < 4; k++) {
            float mean = mv[k] * (1.f / NN);
            float var = qv[k] * (1.f / NN) - mean * mean;
            bs[k] = gv[k] * rsqrtf(var + BN_EPS);
            bt[k] = bbv[k] - mean * bs[k];
        }
    }

    auto gather = [&](uint2 ed, float* acc) {
        const uint2 hz = *(const uint2*)(hsrc + (size_t)ed.x * DD + c0);
        const uint2 bz = *(const uint2*)(bsum_l + (size_t)(ed.y & 0xffff) * DD + c0);
        float w = h2f((unsigned short)(ed.y >> 16));
        unsigned int hw[2] = {hz.x, hz.y}, bw[2] = {bz.x, bz.y};
#pragma unroll
        for (int k = 0; k < 2; k++) {
            float hv0 = h2f((unsigned short)(hw[k] & 0xffff));
            float hv1 = h2f((unsigned short)(hw[k] >> 16));
            if (FUSE) {
                hv0 = fmaxf(hv0 * bs[2 * k] + bt[2 * k], 0.f);
                hv1 = fmaxf(hv1 * bs[2 * k + 1] + bt[2 * k + 1], 0.f);
            }
            float m0 = fmaxf(hv0 + h2f((unsigned short)(bw[k] & 0xffff)), 0.f);
            float m1 = fmaxf(hv1 + h2f((unsigned short)(bw[k] >> 16)), 0.f);
            acc[2 * k] += m0 * w;
            acc[2 * k + 1] += m1 * w;
        }
    };

    int beg = row_ptr[n], end = row_ptr[n + 1];
    float acc[4] = {0.f, 0.f, 0.f, 0.f};
    int i = beg;
    for (; i + 2 <= end; i += 2) {
        uint2 e0 = edata[i], e1 = edata[i + 1];
        gather(e0, acc);
        gather(e1, acc);
    }
    if (i < end) gather(edata[i], acc);

    float eps1 = 1.f + eps_ptr[0];
    uint2 hz = *(const uint2*)(hsrc + (size_t)n * DD + c0);
    unsigned int hw[2] = {hz.x, hz.y};
    float self[4];
#pragma unroll
    for (int k = 0; k < 2; k++) {
        float hv0 = h2f((unsigned short)(hw[k] & 0xffff));
        float hv1 = h2f((unsigned short)(hw[k] >> 16));
        if (FUSE) {
            hv0 = fmaxf(hv0 * bs[2 * k] + bt[2 * k], 0.f);
            hv1 = fmaxf(hv1 * bs[2 * k + 1] + bt[2 * k + 1], 0.f);
        }
        self[2 * k] = hv0;
        self[2 * k + 1] = hv1;
    }
    ushort4 o;
    o.x = f2h_bits(eps1 * self[0] + acc[0]);
    o.y = f2h_bits(eps1 * self[1] + acc[1]);
    o.z = f2h_bits(eps1 * self[2] + acc[2]);
    o.w = f2h_bits(eps1 * self[3] + acc[3]);
    *(ushort4*)(Aout + (size_t)n * DD + c0) = o;
}

// ---------------- persistent fp16 MFMA GEMM, reg-resident B, atomic col stats ----------------
// C(NN x M) = A(NN x K) @ Bt^T + bias, fp16 out. JW = 16-col fragments per wave.
// Block tile: 64 rows x (32*JW) cols. stats[c] += sum, stats[M+c] += sumsq (atomic, fp32).

template <int K, int M, int JW, int GX>
__global__ __launch_bounds__(256, 2) void mfma_gemm_persist(
    const unsigned short* __restrict__ A, const unsigned short* __restrict__ Bt,
    const float* __restrict__ bias, unsigned short* __restrict__ C,
    float* __restrict__ stats) {
    const int KS = K / 32;
    const int GR = (NN + 63) / 64;  // 782
    int wave = threadIdx.x >> 6;
    int lane = threadIdx.x & 63;
    int wr = wave >> 1, wc = wave & 1;
    int col0 = blockIdx.y * (JW * 32) + wc * (JW * 16);
    int lr = lane & 15;
    int q = lane >> 4;

    half8 b[JW][KS];
#pragma unroll
    for (int j = 0; j < JW; j++) {
        const unsigned short* bp = Bt + (size_t)(col0 + j * 16 + lr) * K + q * 8;
#pragma unroll
        for (int ks = 0; ks < KS; ks++)
            b[j][ks] = __builtin_bit_cast(half8, *(const int4*)(bp + ks * 32));
    }

    float bi[JW];
#pragma unroll
    for (int j = 0; j < JW; j++) bi[j] = bias[col0 + j * 16 + lr];

    float s_acc[JW], sq_acc[JW];
#pragma unroll
    for (int j = 0; j < JW; j++) { s_acc[j] = 0.f; sq_acc[j] = 0.f; }

    for (int rb = blockIdx.x; rb < GR; rb += GX) {
        int row0 = rb * 64 + wr * 32;
        half8 a[2][KS];
#pragma unroll
        for (int i = 0; i < 2; i++) {
            int row = row0 + i * 16 + lr;
            const unsigned short* ap = A + (size_t)row * K + q * 8;
#pragma unroll
            for (int ks = 0; ks < KS; ks++) {
                int4 t = {0, 0, 0, 0};
                if (row < NN) t = *(const int4*)(ap + ks * 32);
                a[i][ks] = __builtin_bit_cast(half8, t);
            }
        }

        f32x4 acc[2][JW];
#pragma unroll
        for (int i = 0; i < 2; i++)
#pragma unroll
            for (int j = 0; j < JW; j++) acc[i][j] = (f32x4){0.f, 0.f, 0.f, 0.f};

#pragma unroll
        for (int ks = 0; ks < KS; ks++)
#pragma unroll
            for (int i = 0; i < 2; i++)
#pragma unroll
                for (int j = 0; j < JW; j++)
                    acc[i][j] = __builtin_amdgcn_mfma_f32_16x16x32_f16(a[i][ks], b[j][ks], acc[i][j], 0, 0, 0);

#pragma unroll
        for (int j = 0; j < JW; j++) {
            int c = col0 + j * 16 + lr;
#pragma unroll
            for (int i = 0; i < 2; i++) {
#pragma unroll
                for (int r = 0; r < 4; r++) {
                    int row = row0 + i * 16 + q * 4 + r;
                    if (row < NN) {
                        float v = acc[i][j][r] + bi[j];
                        C[(size_t)row * M + c] = f2h_bits(v);
                        s_acc[j] += v;
                        sq_acc[j] += v * v;
                    }
                }
            }
        }
    }

#pragma unroll
    for (int j = 0; j < JW; j++) {
        int c = col0 + j * 16 + lr;
        float s = s_acc[j], sq = sq_acc[j];
        s += __shfl_xor(s, 16);
        s += __shfl_xor(s, 32);
        sq += __shfl_xor(sq, 16);
        sq += __shfl_xor(sq, 32);
        if (q == 0) {
            unsafeAtomicAdd(&stats[c], s);
            unsafeAtomicAdd(&stats[M + c], sq);
        }
    }
}

// ---------------- BN apply 1 (finalize inline): z1 fp16 -> fp16 relu, M=256, 8/thread --------

__global__ void bnapply1_kernel(const unsigned short* __restrict__ z,
                                const float* __restrict__ stats, const float* __restrict__ g,
                                const float* __restrict__ bb, unsigned short* __restrict__ o) {
    __shared__ float s_sh[DD2], t_sh[DD2];
    {
        int c = threadIdx.x;
        float mean = stats[c] * (1.f / NN);
        float var = stats[DD2 + c] * (1.f / NN) - mean * mean;
        float sc = g[c] * rsqrtf(var + BN_EPS);
        s_sh[c] = sc;
        t_sh[c] = bb[c] - mean * sc;
    }
    __syncthreads();
    int i = (blockIdx.x * 256 + threadIdx.x) * 8;
    int c0 = i & 255;
    uint4 in = *(const uint4*)(z + i);
    unsigned int w[4] = {in.x, in.y, in.z, in.w};
    uint4 out;
    unsigned int* po = (unsigned int*)&out;
#pragma unroll
    for (int k = 0; k < 4; k++) {
        int c = c0 + 2 * k;
        float v0 = fmaxf(h2f((unsigned short)(w[k] & 0xffff)) * s_sh[c] + t_sh[c], 0.f);
        float v1 = fmaxf(h2f((unsigned short)(w[k] >> 16)) * s_sh[c + 1] + t_sh[c + 1], 0.f);
        po[k] = (unsigned int)f2h_bits(v0) | ((unsigned int)f2h_bits(v1) << 16);
    }
    *(uint4*)(o + i) = out;
}

// ---------------- BN apply 2, last layer only: z2 fp16 -> d_out fp32 (no relu) ---------------

__global__ void bnapply2_last_kernel(const unsigned short* __restrict__ z,
                                     const float* __restrict__ stats, const float* __restrict__ g,
                                     const float* __restrict__ bb, float* __restrict__ fout) {
    __shared__ float s_sh[DD], t_sh[DD];
    if (threadIdx.x < DD) {
        int c = threadIdx.x;
        float mean = stats[c] * (1.f / NN);
        float var = stats[DD + c] * (1.f / NN) - mean * mean;
        float sc = g[c] * rsqrtf(var + BN_EPS);
        s_sh[c] = sc;
        t_sh[c] = bb[c] - mean * sc;
    }
    __syncthreads();
    int i = (blockIdx.x * 256 + threadIdx.x) * 4;
    int c = i & 127;
    uint2 in = *(const uint2*)(z + i);
    float4 out;
    out.x = h2f((unsigned short)(in.x & 0xffff)) * s_sh[c] + t_sh[c];
    out.y = h2f((unsigned short)(in.x >> 16)) * s_sh[c + 1] + t_sh[c + 1];
    out.z = h2f((unsigned short)(in.y & 0xffff)) * s_sh[c + 2] + t_sh[c + 2];
    out.w = h2f((unsigned short)(in.y >> 16)) * s_sh[c + 3] + t_sh[c + 3];
    *(float4*)(fout + i) = out;
}

// ---------------- launch ----------------

extern "C" void kernel_launch(void* const* d_in, const int* in_sizes, int n_in,
                              void* d_out, int out_size, void* d_ws, size_t ws_size,
                              hipStream_t stream) {
    const int* x = (const int*)d_in[0];
    const int* edge_index = (const int*)d_in[1];
    const int* edge_attr = (const int*)d_in[2];
    const float* edge_weight = (const float*)d_in[3];
    const float* atom_emb = (const float*)d_in[4];
    const float* bond_emb = (const float*)d_in[5];
    const float* W1 = (const float*)d_in[6];
    const float* b1 = (const float*)d_in[7];
    const float* bn1_g = (const float*)d_in[8];
    const float* bn1_b = (const float*)d_in[9];
    const float* W2 = (const float*)d_in[10];
    const float* b2 = (const float*)d_in[11];
    const float* eps_p = (const float*)d_in[12];
    const float* bn_g = (const float*)d_in[13];
    const float* bn_b = (const float*)d_in[14];
    const int* srcv = edge_index;
    const int* dstv = edge_index + EE;

    char* p = (char*)d_ws;
    auto alloc = [&](size_t bytes) {
        void* r = (void*)p;
        p += (bytes + 255) & ~(size_t)255;
        return r;
    };
    unsigned short* h = (unsigned short*)alloc((size_t)NN * DD * 2);     // layer-0 node state
    unsigned short* A1h = (unsigned short*)alloc((size_t)NN * DD * 2);   // agg out fp16
    unsigned short* z1 = (unsigned short*)alloc((size_t)NN * DD2 * 2);   // gemm1 out fp16
    unsigned short* z1h = (unsigned short*)alloc((size_t)NN * DD2 * 2);  // bn1+relu fp16
    unsigned short* z2 = (unsigned short*)alloc((size_t)NN * DD * 2);    // gemm2 out fp16 (raw)
    uint2* edata = (uint2*)alloc((size_t)EE * 8);
    int* counts = (int*)alloc((size_t)NN * 4);
    int* row_ptr = (int*)alloc((size_t)(NN + 1) * 4);
    int* blksum = (int*)alloc(256 * 4);
    unsigned short* W1t = (unsigned short*)alloc((size_t)LL * DD * DD2 * 2);
    unsigned short* W2t = (unsigned short*)alloc((size_t)LL * DD * DD2 * 2);
    unsigned short* bsum = (unsigned short*)alloc((size_t)LL * 512 * DD * 2);
    float* statsAll = (float*)alloc((size_t)(LL * 512 + LL * 256) * 4);  // 5x[512] gemm1 | 5x[256] gemm2
    float* stats1Base = statsAll;
    float* stats2Base = statsAll + LL * 512;

    // --- one-time prep ---
    hipMemsetAsync(counts, 0, (size_t)NN * 4, stream);
    hipMemsetAsync(statsAll, 0, (size_t)(LL * 512 + LL * 256) * 4, stream);
    hist_kernel<<<(EE + 255) / 256, 256, 0, stream>>>(dstv, counts);
    int nblk = (NN + 255) / 256;
    scan1_kernel<<<nblk, 256, 0, stream>>>(counts, row_ptr, blksum);
    scan2_kernel<<<1, 256, 0, stream>>>(blksum, nblk);
    scan3_kernel<<<nblk, 256, 0, stream>>>(row_ptr, blksum);
    hipMemsetAsync(counts, 0, (size_t)NN * 4, stream);
    scatter_kernel<<<(EE + 255) / 256, 256, 0, stream>>>(dstv, srcv, edge_attr, edge_weight,
                                                         row_ptr, counts, edata);
    prep_tables_kernel<<<(2 * LL * DD * DD2 + LL * 512 * DD + 255) / 256, 256, 0, stream>>>(
        W1, W2, bond_emb, W1t, W2t, bsum);
    init_h_kernel<<<NN / 8, 256, 0, stream>>>(x, atom_emb, h);

    for (int l = 0; l < LL; l++) {
        float* stats1 = stats1Base + l * 512;
        float* stats2 = stats2Base + l * 256;
        const unsigned short* bsum_l = bsum + (size_t)l * 512 * DD;

        if (l == 0) {
            agg_kernel<false><<<NN / 8, 256, 0, stream>>>(h, nullptr, nullptr, nullptr, row_ptr,
                                                          edata, bsum_l, eps_p + l, A1h);
        } else {
            agg_kernel<true><<<NN / 8, 256, 0, stream>>>(
                z2, stats2Base + (l - 1) * 256, bn_g + (l - 1) * DD, bn_b + (l - 1) * DD, row_ptr,
                edata, bsum_l, eps_p + l, A1h);
        }

        // GEMM1: K=128, M=256, JW=4 (block 64x128), grid (128, 2)
        mfma_gemm_persist<DD, DD2, 4, 128><<<dim3(128, 2), 256, 0, stream>>>(
            A1h, W1t + (size_t)l * DD * DD2, b1 + l * DD2, z1, stats1);
        bnapply1_kernel<<<NN * DD2 / 2048, 256, 0, stream>>>(z1, stats1, bn1_g + l * DD2,
                                                             bn1_b + l * DD2, z1h);

        // GEMM2: K=256, M=128, JW=2 (block 64x64), grid (256, 2)
        mfma_gemm_persist<DD2, DD, 2, 256><<<dim3(256, 2), 256, 0, stream>>>(
            z1h, W2t + (size_t)l * DD * DD2, b2 + l * DD, z2, stats2);
    }

    bnapply2_last_kernel<<<NN * DD / 1024, 256, 0, stream>>>(
        z2, stats2Base + (LL - 1) * 256, bn_g + (LL - 1) * DD, bn_b + (LL - 1) * DD,
        (float*)d_out);
}

// Round 8
// 694.140 us; speedup vs baseline: 2.1785x; 1.0141x over previous
//
#include <hip/hip_runtime.h>

#define NN 50000
#define EE 600000
#define DD 128
#define DD2 256
#define LL 5
#define BN_EPS 1e-5f

typedef __attribute__((ext_vector_type(8))) _Float16 half8;
typedef __attribute__((ext_vector_type(4))) float f32x4;

__device__ inline unsigned short f2h_bits(float f) {
    _Float16 h = (_Float16)f;  // RTNE
    return __builtin_bit_cast(unsigned short, h);
}
__device__ inline float h2f(unsigned short u) {
    return (float)__builtin_bit_cast(_Float16, u);
}
__device__ inline half8 bnrelu8(half8 v, half8 s, half8 t) {
    half8 r = v * s + t;
#pragma unroll
    for (int k = 0; k < 8; k++) r[k] = (r[k] > (_Float16)0) ? r[k] : (_Float16)0;
    return r;
}

// ---------------- CSR build ----------------

__global__ void hist_kernel(const int* __restrict__ dst, int* __restrict__ counts) {
    int e = blockIdx.x * blockDim.x + threadIdx.x;
    if (e < EE) atomicAdd(&counts[dst[e]], 1);
}

__global__ void scan1_kernel(const int* __restrict__ counts, int* __restrict__ row_ptr,
                             int* __restrict__ blksum) {
    __shared__ int tmp[256];
    int i = blockIdx.x * 256 + threadIdx.x;
    int v = (i < NN) ? counts[i] : 0;
    tmp[threadIdx.x] = v;
    __syncthreads();
    for (int off = 1; off < 256; off <<= 1) {
        int x = 0;
        if (threadIdx.x >= off) x = tmp[threadIdx.x - off];
        __syncthreads();
        if (threadIdx.x >= off) tmp[threadIdx.x] += x;
        __syncthreads();
    }
    if (i < NN) row_ptr[i] = tmp[threadIdx.x] - v;
    if (threadIdx.x == 255) blksum[blockIdx.x] = tmp[255];
}

__global__ void scan2_kernel(int* __restrict__ blksum, int nblocks) {
    __shared__ int tmp[256];
    int v = (threadIdx.x < nblocks) ? blksum[threadIdx.x] : 0;
    tmp[threadIdx.x] = v;
    __syncthreads();
    for (int off = 1; off < 256; off <<= 1) {
        int x = 0;
        if (threadIdx.x >= off) x = tmp[threadIdx.x - off];
        __syncthreads();
        if (threadIdx.x >= off) tmp[threadIdx.x] += x;
        __syncthreads();
    }
    blksum[threadIdx.x] = tmp[threadIdx.x] - v;
}

__global__ void scan3_kernel(int* __restrict__ row_ptr, const int* __restrict__ blksum) {
    int i = blockIdx.x * 256 + threadIdx.x;
    if (i < NN) row_ptr[i] += blksum[blockIdx.x];
    if (i == 0) row_ptr[NN] = EE;
}

// scatter + pack edge data: edata[p] = {src, cid | w_fp16<<16}
__global__ void scatter_kernel(const int* __restrict__ dst, const int* __restrict__ src,
                               const int* __restrict__ edge_attr, const float* __restrict__ ew,
                               const int* __restrict__ row_ptr, int* __restrict__ cursor,
                               uint2* __restrict__ edata) {
    int e = blockIdx.x * blockDim.x + threadIdx.x;
    if (e < EE) {
        int d = dst[e];
        int p = row_ptr[d] + atomicAdd(&cursor[d], 1);
        int cid = edge_attr[3 * e + 0] + 8 * edge_attr[3 * e + 1] + 64 * edge_attr[3 * e + 2];
        uint2 v;
        v.x = (unsigned)src[e];
        v.y = (unsigned)cid | ((unsigned)f2h_bits(ew[e]) << 16);
        edata[p] = v;
    }
}

// ---------------- table prep: W1t, W2t (fp16, [M][K]) + combined bond table (fp16) ------------

__global__ void prep_tables_kernel(const float* __restrict__ W1, const float* __restrict__ W2,
                                   const float* __restrict__ bond_emb,
                                   unsigned short* __restrict__ W1t,
                                   unsigned short* __restrict__ W2t,
                                   unsigned short* __restrict__ bsum) {
    const int NW = LL * DD * DD2;  // 163840
    int idx = blockIdx.x * 256 + threadIdx.x;
    if (idx < NW) {
        int l = idx / (DD * DD2);
        int rem = idx - l * DD * DD2;
        int k = rem / DD2, m = rem - k * DD2;  // W1: [L][128][256]
        W1t[(size_t)l * DD * DD2 + (size_t)m * DD + k] = f2h_bits(W1[idx]);
    } else if (idx < 2 * NW) {
        int j = idx - NW;
        int l = j / (DD * DD2);
        int rem = j - l * DD * DD2;
        int k = rem / DD, m = rem - k * DD;  // W2: [L][256][128]
        W2t[(size_t)l * DD * DD2 + (size_t)m * DD2 + k] = f2h_bits(W2[j]);
    } else if (idx < 2 * NW + LL * 512 * DD) {
        int j = idx - 2 * NW;
        int l = j >> 16;  // 512*128
        int rem = j & 65535;
        int cid = rem >> 7, d = rem & 127;
        int a0 = cid & 7, a1 = (cid >> 3) & 7, a2 = cid >> 6;
        const float* base = bond_emb + (size_t)l * 3 * 8 * DD;
        bsum[j] = f2h_bits(base[a0 * DD + d] + base[(8 + a1) * DD + d] + base[(16 + a2) * DD + d]);
    }
}

// ---------------- node init (fp16 h0) ----------------

__global__ void init_h_kernel(const int* __restrict__ x, const float* __restrict__ atom_emb,
                              unsigned short* __restrict__ h) {
    int n = blockIdx.x * 8 + (threadIdx.x >> 5);
    int lane = threadIdx.x & 31;
    float a0 = 0.f, a1 = 0.f, a2 = 0.f, a3 = 0.f;
#pragma unroll
    for (int f = 0; f < 9; f++) {
        int idx = x[n * 9 + f];
        const float4 v = *(const float4*)(atom_emb + ((size_t)(f * 64 + idx) * DD) + lane * 4);
        a0 += v.x; a1 += v.y; a2 += v.z; a3 += v.w;
    }
    ushort4 o;
    o.x = f2h_bits(a0); o.y = f2h_bits(a1); o.z = f2h_bits(a2); o.w = f2h_bits(a3);
    *(ushort4*)(h + (size_t)n * DD + lane * 4) = o;
}

// ---------------- edge aggregate → A fp16, optional fused BN2+relu on gathered rows ----------

template <bool FUSE>
__global__ void agg_kernel(const unsigned short* __restrict__ hsrc,
                           const float* __restrict__ stats, const float* __restrict__ g,
                           const float* __restrict__ bb, const int* __restrict__ row_ptr,
                           const uint2* __restrict__ edata,
                           const unsigned short* __restrict__ bsum_l,
                           const float* __restrict__ eps_ptr, unsigned short* __restrict__ Aout) {
    int n = blockIdx.x * 8 + (threadIdx.x >> 5);
    int lane = threadIdx.x & 31;
    int c0 = lane * 4;

    float bs[4] = {1.f, 1.f, 1.f, 1.f}, bt[4] = {0.f, 0.f, 0.f, 0.f};
    if (FUSE) {
        float4 sm = *(const float4*)(stats + c0);
        float4 sq = *(const float4*)(stats + DD + c0);
        float4 gg = *(const float4*)(g + c0);
        float4 bv = *(const float4*)(bb + c0);
        float mv[4] = {sm.x, sm.y, sm.z, sm.w};
        float qv[4] = {sq.x, sq.y, sq.z, sq.w};
        float gv[4] = {gg.x, gg.y, gg.z, gg.w};
        float bbv[4] = {bv.x, bv.y, bv.z, bv.w};
#pragma unroll
        for (int k = 0; k < 4; k++) {
            float mean = mv[k] * (1.f / NN);
            float var = qv[k] * (1.f / NN) - mean * mean;
            bs[k] = gv[k] * rsqrtf(var + BN_EPS);
            bt[k] = bbv[k] - mean * bs[k];
        }
    }

    auto accum = [&](uint2 ed, uint2 hz, uint2 bz, float* acc) {
        float w = h2f((unsigned short)(ed.y >> 16));
        unsigned int hw[2] = {hz.x, hz.y}, bw[2] = {bz.x, bz.y};
#pragma unroll
        for (int k = 0; k < 2; k++) {
            float hv0 = h2f((unsigned short)(hw[k] & 0xffff));
            float hv1 = h2f((unsigned short)(hw[k] >> 16));
            if (FUSE) {
                hv0 = fmaxf(hv0 * bs[2 * k] + bt[2 * k], 0.f);
                hv1 = fmaxf(hv1 * bs[2 * k + 1] + bt[2 * k + 1], 0.f);
            }
            float m0 = fmaxf(hv0 + h2f((unsigned short)(bw[k] & 0xffff)), 0.f);
            float m1 = fmaxf(hv1 + h2f((unsigned short)(bw[k] >> 16)), 0.f);
            acc[2 * k] += m0 * w;
            acc[2 * k + 1] += m1 * w;
        }
    };

    int beg = row_ptr[n], end = row_ptr[n + 1];
    float acc[4] = {0.f, 0.f, 0.f, 0.f};
    int i = beg;
    for (; i + 4 <= end; i += 4) {
        uint2 e0 = edata[i], e1 = edata[i + 1], e2 = edata[i + 2], e3 = edata[i + 3];
        uint2 h0 = *(const uint2*)(hsrc + (size_t)e0.x * DD + c0);
        uint2 b0 = *(const uint2*)(bsum_l + (size_t)(e0.y & 0xffff) * DD + c0);
        uint2 h1 = *(const uint2*)(hsrc + (size_t)e1.x * DD + c0);
        uint2 b1 = *(const uint2*)(bsum_l + (size_t)(e1.y & 0xffff) * DD + c0);
        uint2 h2 = *(const uint2*)(hsrc + (size_t)e2.x * DD + c0);
        uint2 b2 = *(const uint2*)(bsum_l + (size_t)(e2.y & 0xffff) * DD + c0);
        uint2 h3 = *(const uint2*)(hsrc + (size_t)e3.x * DD + c0);
        uint2 b3 = *(const uint2*)(bsum_l + (size_t)(e3.y & 0xffff) * DD + c0);
        accum(e0, h0, b0, acc);
        accum(e1, h1, b1, acc);
        accum(e2, h2, b2, acc);
        accum(e3, h3, b3, acc);
    }
    for (; i < end; i++) {
        uint2 e0 = edata[i];
        uint2 h0 = *(const uint2*)(hsrc + (size_t)e0.x * DD + c0);
        uint2 b0 = *(const uint2*)(bsum_l + (size_t)(e0.y & 0xffff) * DD + c0);
        accum(e0, h0, b0, acc);
    }

    float eps1 = 1.f + eps_ptr[0];
    uint2 hz = *(const uint2*)(hsrc + (size_t)n * DD + c0);
    unsigned int hw[2] = {hz.x, hz.y};
    float self[4];
#pragma unroll
    for (int k = 0; k < 2; k++) {
        float hv0 = h2f((unsigned short)(hw[k] & 0xffff));
        float hv1 = h2f((unsigned short)(hw[k] >> 16));
        if (FUSE) {
            hv0 = fmaxf(hv0 * bs[2 * k] + bt[2 * k], 0.f);
            hv1 = fmaxf(hv1 * bs[2 * k + 1] + bt[2 * k + 1], 0.f);
        }
        self[2 * k] = hv0;
        self[2 * k + 1] = hv1;
    }
    ushort4 o;
    o.x = f2h_bits(eps1 * self[0] + acc[0]);
    o.y = f2h_bits(eps1 * self[1] + acc[1]);
    o.z = f2h_bits(eps1 * self[2] + acc[2]);
    o.w = f2h_bits(eps1 * self[3] + acc[3]);
    *(ushort4*)(Aout + (size_t)n * DD + c0) = o;
}

// ---------------- persistent fp16 MFMA GEMM, reg-resident B, atomic col stats ----------------
// C(NN x M) = act(A)(NN x K) @ Bt^T + bias, fp16 out.
// FUSEA: A-fragments get relu(a*s+t) with s/t from astats/ag/ab (BN1 fused into GEMM2).

template <int K, int M, int JW, int GX, bool FUSEA>
__global__ __launch_bounds__(256, 2) void mfma_gemm_persist(
    const unsigned short* __restrict__ A, const unsigned short* __restrict__ Bt,
    const float* __restrict__ bias, const float* __restrict__ astats,
    const float* __restrict__ ag, const float* __restrict__ ab,
    unsigned short* __restrict__ C, float* __restrict__ stats) {
    const int KS = K / 32;
    const int GR = (NN + 63) / 64;  // 782
    int wave = threadIdx.x >> 6;
    int lane = threadIdx.x & 63;
    int wr = wave >> 1, wc = wave & 1;
    int col0 = blockIdx.y * (JW * 32) + wc * (JW * 16);
    int lr = lane & 15;
    int q = lane >> 4;

    __shared__ _Float16 s_sh[FUSEA ? K : 1], t_sh[FUSEA ? K : 1];
    half8 sa[FUSEA ? KS : 1], ta[FUSEA ? KS : 1];
    if (FUSEA) {
        for (int c = threadIdx.x; c < K; c += 256) {
            float mean = astats[c] * (1.f / NN);
            float var = astats[K + c] * (1.f / NN) - mean * mean;
            float sc = ag[c] * rsqrtf(var + BN_EPS);
            s_sh[c] = (_Float16)sc;
            t_sh[c] = (_Float16)(ab[c] - mean * sc);
        }
        __syncthreads();
#pragma unroll
        for (int ks = 0; ks < KS; ks++) {
            sa[ks] = *(const half8*)(s_sh + ks * 32 + q * 8);
            ta[ks] = *(const half8*)(t_sh + ks * 32 + q * 8);
        }
    }

    half8 b[JW][KS];
#pragma unroll
    for (int j = 0; j < JW; j++) {
        const unsigned short* bp = Bt + (size_t)(col0 + j * 16 + lr) * K + q * 8;
#pragma unroll
        for (int ks = 0; ks < KS; ks++)
            b[j][ks] = __builtin_bit_cast(half8, *(const int4*)(bp + ks * 32));
    }

    float bi[JW];
#pragma unroll
    for (int j = 0; j < JW; j++) bi[j] = bias[col0 + j * 16 + lr];

    float s_acc[JW], sq_acc[JW];
#pragma unroll
    for (int j = 0; j < JW; j++) { s_acc[j] = 0.f; sq_acc[j] = 0.f; }

    for (int rb = blockIdx.x; rb < GR; rb += GX) {
        int row0 = rb * 64 + wr * 32;
        half8 a[2][KS];
#pragma unroll
        for (int i = 0; i < 2; i++) {
            // no bounds guard: OOB rows read benign ws poison, never stored/counted
            const unsigned short* ap = A + (size_t)(row0 + i * 16 + lr) * K + q * 8;
#pragma unroll
            for (int ks = 0; ks < KS; ks++) {
                half8 av = __builtin_bit_cast(half8, *(const int4*)(ap + ks * 32));
                if (FUSEA) av = bnrelu8(av, sa[ks], ta[ks]);
                a[i][ks] = av;
            }
        }

        f32x4 acc[2][JW];
#pragma unroll
        for (int i = 0; i < 2; i++)
#pragma unroll
            for (int j = 0; j < JW; j++) acc[i][j] = (f32x4){0.f, 0.f, 0.f, 0.f};

#pragma unroll
        for (int ks = 0; ks < KS; ks++)
#pragma unroll
            for (int i = 0; i < 2; i++)
#pragma unroll
                for (int j = 0; j < JW; j++)
                    acc[i][j] = __builtin_amdgcn_mfma_f32_16x16x32_f16(a[i][ks], b[j][ks], acc[i][j], 0, 0, 0);

#pragma unroll
        for (int j = 0; j < JW; j++) {
            int c = col0 + j * 16 + lr;
#pragma unroll
            for (int i = 0; i < 2; i++) {
#pragma unroll
                for (int r = 0; r < 4; r++) {
                    int row = row0 + i * 16 + q * 4 + r;
                    if (row < NN) {
                        float v = acc[i][j][r] + bi[j];
                        C[(size_t)row * M + c] = f2h_bits(v);
                        s_acc[j] += v;
                        sq_acc[j] += v * v;
                    }
                }
            }
        }
    }

#pragma unroll
    for (int j = 0; j < JW; j++) {
        int c = col0 + j * 16 + lr;
        float s = s_acc[j], sq = sq_acc[j];
        s += __shfl_xor(s, 16);
        s += __shfl_xor(s, 32);
        sq += __shfl_xor(sq, 16);
        sq += __shfl_xor(sq, 32);
        if (q == 0) {
            unsafeAtomicAdd(&stats[c], s);
            unsafeAtomicAdd(&stats[M + c], sq);
        }
    }
}

// ---------------- BN apply 2, last layer only: z2 fp16 -> d_out fp32 (no relu) ---------------

__global__ void bnapply2_last_kernel(const unsigned short* __restrict__ z,
                                     const float* __restrict__ stats, const float* __restrict__ g,
                                     const float* __restrict__ bb, float* __restrict__ fout) {
    __shared__ float s_sh[DD], t_sh[DD];
    if (threadIdx.x < DD) {
        int c = threadIdx.x;
        float mean = stats[c] * (1.f / NN);
        float var = stats[DD + c] * (1.f / NN) - mean * mean;
        float sc = g[c] * rsqrtf(var + BN_EPS);
        s_sh[c] = sc;
        t_sh[c] = bb[c] - mean * sc;
    }
    __syncthreads();
    int i = (blockIdx.x * 256 + threadIdx.x) * 4;
    int c = i & 127;
    uint2 in = *(const uint2*)(z + i);
    float4 out;
    out.x = h2f((unsigned short)(in.x & 0xffff)) * s_sh[c] + t_sh[c];
    out.y = h2f((unsigned short)(in.x >> 16)) * s_sh[c + 1] + t_sh[c + 1];
    out.z = h2f((unsigned short)(in.y & 0xffff)) * s_sh[c + 2] + t_sh[c + 2];
    out.w = h2f((unsigned short)(in.y >> 16)) * s_sh[c + 3] + t_sh[c + 3];
    *(float4*)(fout + i) = out;
}

// ---------------- launch ----------------

extern "C" void kernel_launch(void* const* d_in, const int* in_sizes, int n_in,
                              void* d_out, int out_size, void* d_ws, size_t ws_size,
                              hipStream_t stream) {
    const int* x = (const int*)d_in[0];
    const int* edge_index = (const int*)d_in[1];
    const int* edge_attr = (const int*)d_in[2];
    const float* edge_weight = (const float*)d_in[3];
    const float* atom_emb = (const float*)d_in[4];
    const float* bond_emb = (const float*)d_in[5];
    const float* W1 = (const float*)d_in[6];
    const float* b1 = (const float*)d_in[7];
    const float* bn1_g = (const float*)d_in[8];
    const float* bn1_b = (const float*)d_in[9];
    const float* W2 = (const float*)d_in[10];
    const float* b2 = (const float*)d_in[11];
    const float* eps_p = (const float*)d_in[12];
    const float* bn_g = (const float*)d_in[13];
    const float* bn_b = (const float*)d_in[14];
    const int* srcv = edge_index;
    const int* dstv = edge_index + EE;

    char* p = (char*)d_ws;
    auto alloc = [&](size_t bytes) {
        void* r = (void*)p;
        p += (bytes + 255) & ~(size_t)255;
        return r;
    };
    unsigned short* h = (unsigned short*)alloc((size_t)NN * DD * 2);    // layer-0 node state
    unsigned short* A1h = (unsigned short*)alloc((size_t)NN * DD * 2);  // agg out fp16
    unsigned short* z1 = (unsigned short*)alloc((size_t)NN * DD2 * 2);  // gemm1 out fp16 (pre-BN)
    unsigned short* z2 = (unsigned short*)alloc((size_t)NN * DD * 2);   // gemm2 out fp16 (pre-BN)
    uint2* edata = (uint2*)alloc((size_t)EE * 8);
    int* counts = (int*)alloc((size_t)NN * 4);
    int* row_ptr = (int*)alloc((size_t)(NN + 1) * 4);
    int* blksum = (int*)alloc(256 * 4);
    unsigned short* W1t = (unsigned short*)alloc((size_t)LL * DD * DD2 * 2);
    unsigned short* W2t = (unsigned short*)alloc((size_t)LL * DD * DD2 * 2);
    unsigned short* bsum = (unsigned short*)alloc((size_t)LL * 512 * DD * 2);
    float* statsAll = (float*)alloc((size_t)(LL * 512 + LL * 256) * 4);
    float* stats1Base = statsAll;
    float* stats2Base = statsAll + LL * 512;

    // --- one-time prep ---
    hipMemsetAsync(counts, 0, (size_t)NN * 4, stream);
    hipMemsetAsync(statsAll, 0, (size_t)(LL * 512 + LL * 256) * 4, stream);
    hist_kernel<<<(EE + 255) / 256, 256, 0, stream>>>(dstv, counts);
    int nblk = (NN + 255) / 256;
    scan1_kernel<<<nblk, 256, 0, stream>>>(counts, row_ptr, blksum);
    scan2_kernel<<<1, 256, 0, stream>>>(blksum, nblk);
    scan3_kernel<<<nblk, 256, 0, stream>>>(row_ptr, blksum);
    hipMemsetAsync(counts, 0, (size_t)NN * 4, stream);
    scatter_kernel<<<(EE + 255) / 256, 256, 0, stream>>>(dstv, srcv, edge_attr, edge_weight,
                                                         row_ptr, counts, edata);
    prep_tables_kernel<<<(2 * LL * DD * DD2 + LL * 512 * DD + 255) / 256, 256, 0, stream>>>(
        W1, W2, bond_emb, W1t, W2t, bsum);
    init_h_kernel<<<NN / 8, 256, 0, stream>>>(x, atom_emb, h);

    for (int l = 0; l < LL; l++) {
        float* stats1 = stats1Base + l * 512;
        float* stats2 = stats2Base + l * 256;
        const unsigned short* bsum_l = bsum + (size_t)l * 512 * DD;

        if (l == 0) {
            agg_kernel<false><<<NN / 8, 256, 0, stream>>>(h, nullptr, nullptr, nullptr, row_ptr,
                                                          edata, bsum_l, eps_p + l, A1h);
        } else {
            agg_kernel<true><<<NN / 8, 256, 0, stream>>>(
                z2, stats2Base + (l - 1) * 256, bn_g + (l - 1) * DD, bn_b + (l - 1) * DD, row_ptr,
                edata, bsum_l, eps_p + l, A1h);
        }

        // GEMM1: K=128, M=256, JW=4, 512 blocks (2/CU)
        mfma_gemm_persist<DD, DD2, 4, 256, false><<<dim3(256, 2), 256, 0, stream>>>(
            A1h, W1t + (size_t)l * DD * DD2, b1 + l * DD2, nullptr, nullptr, nullptr, z1, stats1);

        // GEMM2: K=256, M=128, JW=2, 512 blocks, BN1+relu fused on A
        mfma_gemm_persist<DD2, DD, 2, 256, true><<<dim3(256, 2), 256, 0, stream>>>(
            z1, W2t + (size_t)l * DD * DD2, b2 + l * DD, stats1, bn1_g + l * DD2, bn1_b + l * DD2,
            z2, stats2);
    }

    bnapply2_last_kernel<<<NN * DD / 1024, 256, 0, stream>>>(
        z2, stats2Base + (LL - 1) * 256, bn_g + (LL - 1) * DD, bn_b + (LL - 1) * DD,
        (float*)d_out);
}